// Round 1
// baseline (632.997 us; speedup 1.0000x reference)
//
#include <hip/hip_runtime.h>
#include <hip/hip_bf16.h>

#define NN 50000
#define EE 800000
#define GG 32

// ---------------- CSR build ----------------

__global__ void hist_k(const int* __restrict__ dst, int* __restrict__ cnt, int E) {
    int e = blockIdx.x * blockDim.x + threadIdx.x;
    if (e < E) atomicAdd(&cnt[dst[e]], 1);
}

// exclusive scan of cnt (in-place -> write pointers) + rowptr
__global__ void scan_k(int* __restrict__ cnt_wp, int* __restrict__ rowptr, int N, int E) {
    __shared__ int wsum[16];
    int tid = threadIdx.x;
    int lane = tid & 63;
    int w = tid >> 6;
    int carry = 0;
    for (int base = 0; base < N; base += 1024) {
        int i = base + tid;
        int v = (i < N) ? cnt_wp[i] : 0;
        // wave inclusive scan
        int s = v;
        #pragma unroll
        for (int off = 1; off < 64; off <<= 1) {
            int t = __shfl_up(s, off, 64);
            if (lane >= off) s += t;
        }
        if (lane == 63) wsum[w] = s;
        __syncthreads();
        if (w == 0 && lane < 16) {
            int t = wsum[lane];
            #pragma unroll
            for (int off = 1; off < 16; off <<= 1) {
                int u = __shfl_up(t, off, 64);
                if (lane >= off) t += u;
            }
            wsum[lane] = t;
        }
        __syncthreads();
        int wbase = (w == 0) ? 0 : wsum[w - 1];
        int incl = carry + wbase + s;
        int excl = incl - v;
        if (i < N) { rowptr[i] = excl; cnt_wp[i] = excl; }
        carry += wsum[15];
        __syncthreads();
    }
    if (tid == 0) rowptr[N] = E;
}

__global__ void scatter_k(const int* __restrict__ src, const int* __restrict__ dst,
                          int* __restrict__ wp, int* __restrict__ col, int E) {
    int e = blockIdx.x * blockDim.x + threadIdx.x;
    if (e < E) {
        int p = atomicAdd(&wp[dst[e]], 1);
        col[p] = src[e];
    }
}

// ---------------- input concat ----------------

__global__ void build_inp(const float* __restrict__ nrm, const float* __restrict__ pos,
                          const float* __restrict__ x, float* __restrict__ inp, int N) {
    int t = blockIdx.x * blockDim.x + threadIdx.x;
    if (t >= N * 8) return;
    int i = t >> 3, f = t & 7;
    float v;
    if (f < 3) v = nrm[i * 3 + f];
    else if (f < 6) v = pos[i * 3 + (f - 3)];
    else v = x[i * 2 + (f - 6)];
    inp[t] = v;
}

// W3' : fold duplicated inp rows (200:208) into (64:72). [200][256]
__global__ void build_w3p(const float* __restrict__ W3, float* __restrict__ W3p) {
    int t = blockIdx.x * blockDim.x + threadIdx.x;
    if (t >= 200 * 256) return;
    int k = t / 256, f = t % 256;
    float v = W3[t];
    if (k >= 64 && k < 72) v += W3[(k + 136) * 256 + f];
    W3p[t] = v;
}

// ---------------- aggregation: dst[i,f] = sum_{e in row i} src[col[e], f] ----------------

template <int F>
__global__ __launch_bounds__(256) void agg_k(const int* __restrict__ rowptr,
                                             const int* __restrict__ col,
                                             const float* __restrict__ src,
                                             float* __restrict__ dst, int N) {
    const int Q = 256 / F;
    int i = blockIdx.x * Q + threadIdx.x / F;
    int f = threadIdx.x % F;
    if (i >= N) return;
    int e0 = rowptr[i], e1 = rowptr[i + 1];
    float acc = 0.f;
    for (int e = e0; e < e1; e++) {
        int s = col[e];
        acc += src[(size_t)s * F + f];
    }
    dst[(size_t)i * F + f] = acc;
}

// ---------------- fused dense transform: out = relu(concat(inA,inB,inC) @ W + b) ----------------
// block = F threads, M nodes per block; optional fused global-max-pool epilogue.

template <int K, int F, int M, int WA, int WB, int WC, bool POOL>
__global__ __launch_bounds__(F) void transform_k(const float* __restrict__ inA,
                                                 const float* __restrict__ inB,
                                                 const float* __restrict__ inC,
                                                 const float* __restrict__ W,
                                                 const float* __restrict__ bias,
                                                 float* __restrict__ out,
                                                 const int* __restrict__ batch,
                                                 float* __restrict__ pooled, int N) {
    __shared__ float rows[M][K];
    int node0 = blockIdx.x * M;
    int f = threadIdx.x;

    for (int idx = threadIdx.x; idx < M * K; idx += F) {
        int m = idx / K, k = idx % K;
        int i = node0 + m;
        float v = 0.f;
        if (i < N) {
            if (k < WA) v = inA[(size_t)i * WA + k];
            else if (k < WA + WB) v = inB[(size_t)i * WB + (k - WA)];
            else v = inC[(size_t)i * WC + (k - WA - WB)];
        }
        rows[m][k] = v;
    }
    __syncthreads();

    float acc[M];
    float b = bias[f];
    #pragma unroll
    for (int m = 0; m < M; m++) acc[m] = b;

    for (int k = 0; k < K; k += 4) {
        float w0 = W[(size_t)(k + 0) * F + f];
        float w1 = W[(size_t)(k + 1) * F + f];
        float w2 = W[(size_t)(k + 2) * F + f];
        float w3 = W[(size_t)(k + 3) * F + f];
        #pragma unroll
        for (int m = 0; m < M; m++) {
            float4 r = *reinterpret_cast<const float4*>(&rows[m][k]);
            acc[m] = fmaf(r.x, w0, fmaf(r.y, w1, fmaf(r.z, w2, fmaf(r.w, w3, acc[m]))));
        }
    }

    for (int m = 0; m < M; m++) {
        int i = node0 + m;
        if (i >= N) break;
        float v = fmaxf(acc[m], 0.f);
        if (POOL) {
            int g = batch[i];
            atomicMax(reinterpret_cast<int*>(&pooled[(size_t)g * F + f]), __float_as_int(v));
        } else {
            out[(size_t)i * F + f] = v;
        }
    }
}

// ---------------- head: logits -> log_softmax, softmax ----------------

__global__ __launch_bounds__(320) void head_k(const float* __restrict__ pooled,
                                              const float* __restrict__ Wl,
                                              const float* __restrict__ bl,
                                              float* __restrict__ out) {
    __shared__ float lg[GG][10];
    __shared__ float lse[GG];
    int t = threadIdx.x;
    int g = t / 10, c = t % 10;
    float acc = bl[c];
    for (int k = 0; k < 256; k++) acc = fmaf(pooled[g * 256 + k], Wl[k * 10 + c], acc);
    lg[g][c] = acc;
    __syncthreads();
    if (c == 0) {
        float mx = -1e30f;
        for (int j = 0; j < 10; j++) mx = fmaxf(mx, lg[g][j]);
        float s = 0.f;
        for (int j = 0; j < 10; j++) s += expf(lg[g][j] - mx);
        lse[g] = mx + logf(s);
    }
    __syncthreads();
    float o = acc - lse[g];
    out[g * 10 + c] = o;            // log_softmax
    out[320 + g * 10 + c] = expf(o); // softmax(log_softmax(x)) == exp(log_softmax(x))
}

// ---------------- launch ----------------

extern "C" void kernel_launch(void* const* d_in, const int* in_sizes, int n_in,
                              void* d_out, int out_size, void* d_ws, size_t ws_size,
                              hipStream_t stream) {
    const int N = NN, E = EE;
    const float* nrm = (const float*)d_in[0];
    const float* pos = (const float*)d_in[1];
    const float* x   = (const float*)d_in[2];
    const int* ei    = (const int*)d_in[3];
    const int* batch = (const int*)d_in[4];
    const float* W1 = (const float*)d_in[5];
    const float* b1 = (const float*)d_in[6];
    const float* W2 = (const float*)d_in[7];
    const float* b2 = (const float*)d_in[8];
    const float* W3 = (const float*)d_in[9];
    const float* b3 = (const float*)d_in[10];
    const float* Wl = (const float*)d_in[11];
    const float* bl = (const float*)d_in[12];

    const int* esrc = ei;
    const int* edst = ei + E;

    // workspace carve (256B aligned)
    char* w = (char*)d_ws;
    auto carve = [&](size_t bytes) {
        void* p = (void*)w;
        w += (bytes + 255) & ~(size_t)255;
        return p;
    };
    int* wp      = (int*)carve((size_t)N * 4);
    int* rowptr  = (int*)carve((size_t)(N + 1) * 4);
    int* col     = (int*)carve((size_t)E * 4);
    float* inp   = (float*)carve((size_t)N * 8 * 4);
    float* agg1  = (float*)carve((size_t)N * 8 * 4);
    float* aggh1 = (float*)carve((size_t)N * 64 * 4);
    float* h2    = (float*)carve((size_t)N * 128 * 4);
    float* aggh2 = (float*)carve((size_t)N * 128 * 4);
    float* h1    = aggh2; // alias: h1 dead before aggh2 is written
    float* W3p   = (float*)carve((size_t)200 * 256 * 4);
    float* pooled= (float*)carve((size_t)GG * 256 * 4);

    hipMemsetAsync(wp, 0, (size_t)N * 4, stream);
    hipMemsetAsync(pooled, 0, (size_t)GG * 256 * 4, stream);

    hist_k<<<(E + 255) / 256, 256, 0, stream>>>(edst, wp, E);
    scan_k<<<1, 1024, 0, stream>>>(wp, rowptr, N, E);
    scatter_k<<<(E + 255) / 256, 256, 0, stream>>>(esrc, edst, wp, col, E);

    build_inp<<<(N * 8 + 255) / 256, 256, 0, stream>>>(nrm, pos, x, inp, N);
    build_w3p<<<(200 * 256 + 255) / 256, 256, 0, stream>>>(W3, W3p);

    // layer 1: agg1 = A @ inp ; h1 = relu(agg1 @ W1 + b1)
    agg_k<8><<<(N + 31) / 32, 256, 0, stream>>>(rowptr, col, inp, agg1, N);
    transform_k<8, 64, 32, 8, 0, 0, false><<<(N + 31) / 32, 64, 0, stream>>>(
        agg1, nullptr, nullptr, W1, b1, h1, nullptr, nullptr, N);

    // layer 2: aggh1 = A @ h1 ; h2 = relu([aggh1|agg1] @ W2 + b2)
    agg_k<64><<<(N + 3) / 4, 256, 0, stream>>>(rowptr, col, h1, aggh1, N);
    transform_k<72, 128, 32, 64, 8, 0, false><<<(N + 31) / 32, 128, 0, stream>>>(
        aggh1, agg1, nullptr, W2, b2, h2, nullptr, nullptr, N);

    // layer 3: aggh2 = A @ h2 ; h3 = relu([aggh1|agg1|aggh2] @ W3' + b3) fused with max-pool
    agg_k<128><<<(N + 1) / 2, 256, 0, stream>>>(rowptr, col, h2, aggh2, N);
    transform_k<200, 256, 32, 64, 8, 128, true><<<(N + 31) / 32, 256, 0, stream>>>(
        aggh1, agg1, aggh2, W3p, b3, nullptr, batch, pooled, N);

    head_k<<<1, 320, 0, stream>>>(pooled, Wl, bl, (float*)d_out);
}

// Round 2
// 572.334 us; speedup vs baseline: 1.1060x; 1.1060x over previous
//
#include <hip/hip_runtime.h>
#include <hip/hip_bf16.h>

#define NN 50000
#define EE 800000
#define GG 32

// ---------------- CSR build ----------------

__global__ void hist_k(const int* __restrict__ dst, int* __restrict__ cnt, int E) {
    int e = blockIdx.x * blockDim.x + threadIdx.x;
    if (e < E) atomicAdd(&cnt[dst[e]], 1);
}

// exclusive scan of cnt (in-place -> write pointers) + rowptr
__global__ void scan_k(int* __restrict__ cnt_wp, int* __restrict__ rowptr, int N, int E) {
    __shared__ int wsum[16];
    int tid = threadIdx.x;
    int lane = tid & 63;
    int w = tid >> 6;
    int carry = 0;
    for (int base = 0; base < N; base += 1024) {
        int i = base + tid;
        int v = (i < N) ? cnt_wp[i] : 0;
        int s = v;
        #pragma unroll
        for (int off = 1; off < 64; off <<= 1) {
            int t = __shfl_up(s, off, 64);
            if (lane >= off) s += t;
        }
        if (lane == 63) wsum[w] = s;
        __syncthreads();
        if (w == 0 && lane < 16) {
            int t = wsum[lane];
            #pragma unroll
            for (int off = 1; off < 16; off <<= 1) {
                int u = __shfl_up(t, off, 64);
                if (lane >= off) t += u;
            }
            wsum[lane] = t;
        }
        __syncthreads();
        int wbase = (w == 0) ? 0 : wsum[w - 1];
        int incl = carry + wbase + s;
        int excl = incl - v;
        if (i < N) { rowptr[i] = excl; cnt_wp[i] = excl; }
        carry += wsum[15];
        __syncthreads();
    }
    if (tid == 0) rowptr[N] = E;
}

__global__ void scatter_k(const int* __restrict__ src, const int* __restrict__ dst,
                          int* __restrict__ wp, int* __restrict__ col, int E) {
    int e = blockIdx.x * blockDim.x + threadIdx.x;
    if (e < E) {
        int p = atomicAdd(&wp[dst[e]], 1);
        col[p] = src[e];
    }
}

// ---------------- input concat ----------------

__global__ void build_inp(const float* __restrict__ nrm, const float* __restrict__ pos,
                          const float* __restrict__ x, float* __restrict__ inp, int N) {
    int t = blockIdx.x * blockDim.x + threadIdx.x;
    if (t >= N * 8) return;
    int i = t >> 3, f = t & 7;
    float v;
    if (f < 3) v = nrm[i * 3 + f];
    else if (f < 6) v = pos[i * 3 + (f - 3)];
    else v = x[i * 2 + (f - 6)];
    inp[t] = v;
}

// W3' : fold duplicated inp rows (200:208) into (64:72). [200][256]
__global__ void build_w3p(const float* __restrict__ W3, float* __restrict__ W3p) {
    int t = blockIdx.x * blockDim.x + threadIdx.x;
    if (t >= 200 * 256) return;
    int k = t / 256, f = t % 256;
    float v = W3[t];
    if (k >= 64 && k < 72) v += W3[(k + 136) * 256 + f];
    W3p[t] = v;
}

// ---------------- aggregation: dst[i,f] = sum_{e in row i} src[col[e], f] ----------------

template <int F>
__global__ __launch_bounds__(256) void agg_k(const int* __restrict__ rowptr,
                                             const int* __restrict__ col,
                                             const float* __restrict__ src,
                                             float* __restrict__ dst, int N) {
    const int Q = 256 / F;
    int i = blockIdx.x * Q + threadIdx.x / F;
    int f = threadIdx.x % F;
    if (i >= N) return;
    int e0 = rowptr[i], e1 = rowptr[i + 1];
    float acc = 0.f;
    for (int e = e0; e < e1; e++) {
        int s = col[e];
        acc += src[(size_t)s * F + f];
    }
    dst[(size_t)i * F + f] = acc;
}

// ---------------- fused dense transform ----------------
// out = relu(concat(inA,inB,inC) @ W + b); optional fused segment-max pool.
// Block: GROUPS node-groups x (F/CPT) column-threads; each thread owns CPT
// columns (c, c+F/CPT, ...) for MPG nodes. Each ds_read_b128 of a row
// fragment feeds 4*CPT FMAs. Pool uses batch-sorted graph-change flushing
// (~1 atomic per thread instead of MPG atomics per thread).

template <int K, int F, int MPG, int GROUPS, int CPT, int WA, int WB, int WC, bool POOL>
__global__ __launch_bounds__(GROUPS*(F/CPT)) void transform_k(
        const float* __restrict__ inA, const float* __restrict__ inB,
        const float* __restrict__ inC, const float* __restrict__ W,
        const float* __restrict__ bias, float* __restrict__ out,
        const int* __restrict__ batch, float* __restrict__ pooled, int N) {
    constexpr int FC = F / CPT;
    constexpr int BLOCK = GROUPS * FC;
    constexpr int M = GROUPS * MPG;
    __shared__ float rows[M][K];
    const int node0 = blockIdx.x * M;
    const int tid = threadIdx.x;

    // ---- stage sources into LDS (float4, all sub-offsets 16B-aligned) ----
    {
        constexpr int NA = WA / 4;
        for (int idx = tid; idx < M * NA; idx += BLOCK) {
            int m = idx / NA, q = idx - m * NA;
            int i = node0 + m;
            float4 v = make_float4(0.f, 0.f, 0.f, 0.f);
            if (i < N) v = *reinterpret_cast<const float4*>(&inA[(size_t)i * WA + q * 4]);
            *reinterpret_cast<float4*>(&rows[m][q * 4]) = v;
        }
    }
    if constexpr (WB > 0) {
        constexpr int NB = WB / 4;
        for (int idx = tid; idx < M * NB; idx += BLOCK) {
            int m = idx / NB, q = idx - m * NB;
            int i = node0 + m;
            float4 v = make_float4(0.f, 0.f, 0.f, 0.f);
            if (i < N) v = *reinterpret_cast<const float4*>(&inB[(size_t)i * WB + q * 4]);
            *reinterpret_cast<float4*>(&rows[m][WA + q * 4]) = v;
        }
    }
    if constexpr (WC > 0) {
        constexpr int NC = WC / 4;
        for (int idx = tid; idx < M * NC; idx += BLOCK) {
            int m = idx / NC, q = idx - m * NC;
            int i = node0 + m;
            float4 v = make_float4(0.f, 0.f, 0.f, 0.f);
            if (i < N) v = *reinterpret_cast<const float4*>(&inC[(size_t)i * WC + q * 4]);
            *reinterpret_cast<float4*>(&rows[m][WA + WB + q * 4]) = v;
        }
    }
    __syncthreads();

    const int g = tid / FC;
    const int c = tid - g * FC;

    float acc[MPG][CPT];
    #pragma unroll
    for (int j = 0; j < CPT; j++) {
        float bv = bias[c + j * FC];
        #pragma unroll
        for (int m = 0; m < MPG; m++) acc[m][j] = bv;
    }

    for (int k = 0; k < K; k += 4) {
        float w[CPT][4];
        #pragma unroll
        for (int j = 0; j < CPT; j++)
            #pragma unroll
            for (int kk = 0; kk < 4; kk++)
                w[j][kk] = W[(size_t)(k + kk) * F + c + j * FC];
        #pragma unroll
        for (int m = 0; m < MPG; m++) {
            float4 r = *reinterpret_cast<const float4*>(&rows[g * MPG + m][k]);
            #pragma unroll
            for (int j = 0; j < CPT; j++)
                acc[m][j] = fmaf(r.x, w[j][0], fmaf(r.y, w[j][1],
                             fmaf(r.z, w[j][2], fmaf(r.w, w[j][3], acc[m][j]))));
        }
    }

    if constexpr (POOL) {
        int curg = -1;
        float cm[CPT];
        #pragma unroll
        for (int j = 0; j < CPT; j++) cm[j] = 0.f;
        for (int m = 0; m < MPG; m++) {
            int i = node0 + g * MPG + m;
            if (i >= N) break;
            int bg = batch[i];
            if (bg != curg) {
                if (curg >= 0) {
                    #pragma unroll
                    for (int j = 0; j < CPT; j++)
                        atomicMax(reinterpret_cast<int*>(&pooled[(size_t)curg * F + c + j * FC]),
                                  __float_as_int(cm[j]));
                }
                curg = bg;
                #pragma unroll
                for (int j = 0; j < CPT; j++) cm[j] = 0.f;
            }
            #pragma unroll
            for (int j = 0; j < CPT; j++)
                cm[j] = fmaxf(cm[j], fmaxf(acc[m][j], 0.f));
        }
        if (curg >= 0) {
            #pragma unroll
            for (int j = 0; j < CPT; j++)
                atomicMax(reinterpret_cast<int*>(&pooled[(size_t)curg * F + c + j * FC]),
                          __float_as_int(cm[j]));
        }
    } else {
        for (int m = 0; m < MPG; m++) {
            int i = node0 + g * MPG + m;
            if (i >= N) break;
            #pragma unroll
            for (int j = 0; j < CPT; j++)
                out[(size_t)i * F + c + j * FC] = fmaxf(acc[m][j], 0.f);
        }
    }
}

// ---------------- head: logits -> log_softmax, softmax ----------------

__global__ __launch_bounds__(320) void head_k(const float* __restrict__ pooled,
                                              const float* __restrict__ Wl,
                                              const float* __restrict__ bl,
                                              float* __restrict__ out) {
    __shared__ float lg[GG][10];
    __shared__ float lse[GG];
    int t = threadIdx.x;
    int g = t / 10, c = t % 10;
    float acc = bl[c];
    for (int k = 0; k < 256; k++) acc = fmaf(pooled[g * 256 + k], Wl[k * 10 + c], acc);
    lg[g][c] = acc;
    __syncthreads();
    if (c == 0) {
        float mx = -1e30f;
        for (int j = 0; j < 10; j++) mx = fmaxf(mx, lg[g][j]);
        float s = 0.f;
        for (int j = 0; j < 10; j++) s += expf(lg[g][j] - mx);
        lse[g] = mx + logf(s);
    }
    __syncthreads();
    float o = acc - lse[g];
    out[g * 10 + c] = o;             // log_softmax
    out[320 + g * 10 + c] = expf(o); // softmax(log_softmax(x)) == exp(log_softmax(x))
}

// ---------------- launch ----------------

extern "C" void kernel_launch(void* const* d_in, const int* in_sizes, int n_in,
                              void* d_out, int out_size, void* d_ws, size_t ws_size,
                              hipStream_t stream) {
    const int N = NN, E = EE;
    const float* nrm = (const float*)d_in[0];
    const float* pos = (const float*)d_in[1];
    const float* x   = (const float*)d_in[2];
    const int* ei    = (const int*)d_in[3];
    const int* batch = (const int*)d_in[4];
    const float* W1 = (const float*)d_in[5];
    const float* b1 = (const float*)d_in[6];
    const float* W2 = (const float*)d_in[7];
    const float* b2 = (const float*)d_in[8];
    const float* W3 = (const float*)d_in[9];
    const float* b3 = (const float*)d_in[10];
    const float* Wl = (const float*)d_in[11];
    const float* bl = (const float*)d_in[12];

    const int* esrc = ei;
    const int* edst = ei + E;

    char* w = (char*)d_ws;
    auto carve = [&](size_t bytes) {
        void* p = (void*)w;
        w += (bytes + 255) & ~(size_t)255;
        return p;
    };
    int* wp      = (int*)carve((size_t)N * 4);
    int* rowptr  = (int*)carve((size_t)(N + 1) * 4);
    int* col     = (int*)carve((size_t)E * 4);
    float* inp   = (float*)carve((size_t)N * 8 * 4);
    float* agg1  = (float*)carve((size_t)N * 8 * 4);
    float* aggh1 = (float*)carve((size_t)N * 64 * 4);
    float* h2    = (float*)carve((size_t)N * 128 * 4);
    float* aggh2 = (float*)carve((size_t)N * 128 * 4);
    float* h1    = aggh2; // alias: h1 dead before aggh2 is written
    float* W3p   = (float*)carve((size_t)200 * 256 * 4);
    float* pooled= (float*)carve((size_t)GG * 256 * 4);

    hipMemsetAsync(wp, 0, (size_t)N * 4, stream);
    hipMemsetAsync(pooled, 0, (size_t)GG * 256 * 4, stream);

    hist_k<<<(E + 255) / 256, 256, 0, stream>>>(edst, wp, E);
    scan_k<<<1, 1024, 0, stream>>>(wp, rowptr, N, E);
    scatter_k<<<(E + 255) / 256, 256, 0, stream>>>(esrc, edst, wp, col, E);

    build_inp<<<(N * 8 + 255) / 256, 256, 0, stream>>>(nrm, pos, x, inp, N);
    build_w3p<<<(200 * 256 + 255) / 256, 256, 0, stream>>>(W3, W3p);

    // layer 1: agg1 = A @ inp ; h1 = relu(agg1 @ W1 + b1)
    agg_k<8><<<(N + 31) / 32, 256, 0, stream>>>(rowptr, col, inp, agg1, N);
    transform_k<8, 64, 32, 4, 1, 8, 0, 0, false><<<(N + 127) / 128, 256, 0, stream>>>(
        agg1, nullptr, nullptr, W1, b1, h1, nullptr, nullptr, N);

    // layer 2: aggh1 = A @ h1 ; h2 = relu([aggh1|agg1] @ W2 + b2)
    agg_k<64><<<(N + 3) / 4, 256, 0, stream>>>(rowptr, col, h1, aggh1, N);
    transform_k<72, 128, 32, 4, 2, 64, 8, 0, false><<<(N + 127) / 128, 256, 0, stream>>>(
        aggh1, agg1, nullptr, W2, b2, h2, nullptr, nullptr, N);

    // layer 3: aggh2 = A @ h2 ; pooled = segmax(relu([aggh1|agg1|aggh2] @ W3' + b3))
    agg_k<128><<<(N + 1) / 2, 256, 0, stream>>>(rowptr, col, h2, aggh2, N);
    transform_k<200, 256, 32, 2, 2, 64, 8, 128, true><<<(N + 63) / 64, 256, 0, stream>>>(
        aggh1, agg1, aggh2, W3p, b3, nullptr, batch, pooled, N);

    head_k<<<1, 320, 0, stream>>>(pooled, Wl, bl, (float*)d_out);
}

// Round 3
// 385.827 us; speedup vs baseline: 1.6406x; 1.4834x over previous
//
#include <hip/hip_runtime.h>
#include <hip/hip_bf16.h>

#define NN 50000
#define EE 800000
#define GG 32

// ---------------- CSR build ----------------

__global__ void hist_k(const int* __restrict__ dst, int* __restrict__ cnt, int E) {
    int e = blockIdx.x * blockDim.x + threadIdx.x;
    if (e < E) atomicAdd(&cnt[dst[e]], 1);
}

// exclusive scan of cnt (in-place -> write pointers) + rowptr
__global__ void scan_k(int* __restrict__ cnt_wp, int* __restrict__ rowptr, int N, int E) {
    __shared__ int wsum[16];
    int tid = threadIdx.x;
    int lane = tid & 63;
    int w = tid >> 6;
    int carry = 0;
    for (int base = 0; base < N; base += 1024) {
        int i = base + tid;
        int v = (i < N) ? cnt_wp[i] : 0;
        int s = v;
        #pragma unroll
        for (int off = 1; off < 64; off <<= 1) {
            int t = __shfl_up(s, off, 64);
            if (lane >= off) s += t;
        }
        if (lane == 63) wsum[w] = s;
        __syncthreads();
        if (w == 0 && lane < 16) {
            int t = wsum[lane];
            #pragma unroll
            for (int off = 1; off < 16; off <<= 1) {
                int u = __shfl_up(t, off, 64);
                if (lane >= off) t += u;
            }
            wsum[lane] = t;
        }
        __syncthreads();
        int wbase = (w == 0) ? 0 : wsum[w - 1];
        int incl = carry + wbase + s;
        int excl = incl - v;
        if (i < N) { rowptr[i] = excl; cnt_wp[i] = excl; }
        carry += wsum[15];
        __syncthreads();
    }
    if (tid == 0) rowptr[N] = E;
}

__global__ void scatter_k(const int* __restrict__ src, const int* __restrict__ dst,
                          int* __restrict__ wp, int* __restrict__ col, int E) {
    int e = blockIdx.x * blockDim.x + threadIdx.x;
    if (e < E) {
        int p = atomicAdd(&wp[dst[e]], 1);
        col[p] = src[e];
    }
}

// ---------------- input concat ----------------

__global__ void build_inp(const float* __restrict__ nrm, const float* __restrict__ pos,
                          const float* __restrict__ x, float* __restrict__ inp, int N) {
    int t = blockIdx.x * blockDim.x + threadIdx.x;
    if (t >= N * 8) return;
    int i = t >> 3, f = t & 7;
    float v;
    if (f < 3) v = nrm[i * 3 + f];
    else if (f < 6) v = pos[i * 3 + (f - 3)];
    else v = x[i * 2 + (f - 6)];
    inp[t] = v;
}

// W3' : fold duplicated inp rows (200:208) into (64:72). [200][256]
__global__ void build_w3p(const float* __restrict__ W3, float* __restrict__ W3p) {
    int t = blockIdx.x * blockDim.x + threadIdx.x;
    if (t >= 200 * 256) return;
    int k = t / 256, f = t % 256;
    float v = W3[t];
    if (k >= 64 && k < 72) v += W3[(k + 136) * 256 + f];
    W3p[t] = v;
}

// ---------------- aggregation: dst[i,f] = sum_{e in row i} src[col[e], f] ----------------
// float4 per thread (F/4 threads per node), 2-edge unroll for load ILP.

template <int F>
__global__ __launch_bounds__(256) void agg4_k(const int* __restrict__ rowptr,
                                              const int* __restrict__ col,
                                              const float* __restrict__ src,
                                              float* __restrict__ dst, int N) {
    constexpr int TPN = F / 4;
    constexpr int Q = 256 / TPN;
    int i = blockIdx.x * Q + threadIdx.x / TPN;
    int f4 = (threadIdx.x % TPN) * 4;
    if (i >= N) return;
    int e0 = rowptr[i], e1 = rowptr[i + 1];
    float4 a0 = make_float4(0.f, 0.f, 0.f, 0.f);
    float4 a1 = make_float4(0.f, 0.f, 0.f, 0.f);
    int e = e0;
    for (; e + 1 < e1; e += 2) {
        int s0 = col[e], s1 = col[e + 1];
        float4 v0 = *reinterpret_cast<const float4*>(&src[(size_t)s0 * F + f4]);
        float4 v1 = *reinterpret_cast<const float4*>(&src[(size_t)s1 * F + f4]);
        a0.x += v0.x; a0.y += v0.y; a0.z += v0.z; a0.w += v0.w;
        a1.x += v1.x; a1.y += v1.y; a1.z += v1.z; a1.w += v1.w;
    }
    if (e < e1) {
        int s0 = col[e];
        float4 v0 = *reinterpret_cast<const float4*>(&src[(size_t)s0 * F + f4]);
        a0.x += v0.x; a0.y += v0.y; a0.z += v0.z; a0.w += v0.w;
    }
    a0.x += a1.x; a0.y += a1.y; a0.z += a1.z; a0.w += a1.w;
    *reinterpret_cast<float4*>(&dst[(size_t)i * F + f4]) = a0;
}

// ---------------- fused dense transform ----------------
// out = relu(concat(inA,inB,inC) @ W + b); optional fused segment-max pool.
// GROUPS node-groups x FC column-threads (512-thread blocks for occupancy);
// each thread owns CPT columns for MPG nodes. Broadcast ds_read_b128 row
// fragments feed 4*CPT FMAs each; W prefetched one k-step ahead.

template <int K, int F, int MPG, int GROUPS, int CPT, int WA, int WB, int WC, bool POOL>
__global__ __launch_bounds__(GROUPS*(F/CPT), 6) void transform_k(
        const float* __restrict__ inA, const float* __restrict__ inB,
        const float* __restrict__ inC, const float* __restrict__ W,
        const float* __restrict__ bias, float* __restrict__ out,
        const int* __restrict__ batch, float* __restrict__ pooled, int N) {
    constexpr int FC = F / CPT;
    constexpr int BLOCK = GROUPS * FC;
    constexpr int M = GROUPS * MPG;
    __shared__ float rows[M][K];
    const int node0 = blockIdx.x * M;
    const int tid = threadIdx.x;

    // ---- stage sources into LDS (float4, all sub-offsets 16B-aligned) ----
    {
        constexpr int NA = WA / 4;
        for (int idx = tid; idx < M * NA; idx += BLOCK) {
            int m = idx / NA, q = idx - m * NA;
            int i = node0 + m;
            float4 v = make_float4(0.f, 0.f, 0.f, 0.f);
            if (i < N) v = *reinterpret_cast<const float4*>(&inA[(size_t)i * WA + q * 4]);
            *reinterpret_cast<float4*>(&rows[m][q * 4]) = v;
        }
    }
    if constexpr (WB > 0) {
        constexpr int NB = WB / 4;
        for (int idx = tid; idx < M * NB; idx += BLOCK) {
            int m = idx / NB, q = idx - m * NB;
            int i = node0 + m;
            float4 v = make_float4(0.f, 0.f, 0.f, 0.f);
            if (i < N) v = *reinterpret_cast<const float4*>(&inB[(size_t)i * WB + q * 4]);
            *reinterpret_cast<float4*>(&rows[m][WA + q * 4]) = v;
        }
    }
    if constexpr (WC > 0) {
        constexpr int NC = WC / 4;
        for (int idx = tid; idx < M * NC; idx += BLOCK) {
            int m = idx / NC, q = idx - m * NC;
            int i = node0 + m;
            float4 v = make_float4(0.f, 0.f, 0.f, 0.f);
            if (i < N) v = *reinterpret_cast<const float4*>(&inC[(size_t)i * WC + q * 4]);
            *reinterpret_cast<float4*>(&rows[m][WA + WB + q * 4]) = v;
        }
    }
    __syncthreads();

    const int g = tid / FC;
    const int c = tid - g * FC;

    float acc[MPG][CPT];
    #pragma unroll
    for (int j = 0; j < CPT; j++) {
        float bv = bias[c + j * FC];
        #pragma unroll
        for (int m = 0; m < MPG; m++) acc[m][j] = bv;
    }

    float w[CPT][4];
    #pragma unroll
    for (int j = 0; j < CPT; j++)
        #pragma unroll
        for (int kk = 0; kk < 4; kk++)
            w[j][kk] = W[(size_t)kk * F + c + j * FC];

    for (int k = 0; k < K; k += 4) {
        // prefetch next k-step's W while computing this one
        int kn = (k + 4 < K) ? (k + 4) : k;
        float wn[CPT][4];
        #pragma unroll
        for (int j = 0; j < CPT; j++)
            #pragma unroll
            for (int kk = 0; kk < 4; kk++)
                wn[j][kk] = W[(size_t)(kn + kk) * F + c + j * FC];

        #pragma unroll
        for (int m = 0; m < MPG; m++) {
            float4 r = *reinterpret_cast<const float4*>(&rows[g * MPG + m][k]);
            #pragma unroll
            for (int j = 0; j < CPT; j++)
                acc[m][j] = fmaf(r.x, w[j][0], fmaf(r.y, w[j][1],
                             fmaf(r.z, w[j][2], fmaf(r.w, w[j][3], acc[m][j]))));
        }
        #pragma unroll
        for (int j = 0; j < CPT; j++)
            #pragma unroll
            for (int kk = 0; kk < 4; kk++)
                w[j][kk] = wn[j][kk];
    }

    if constexpr (POOL) {
        int curg = -1;
        float cm[CPT];
        #pragma unroll
        for (int j = 0; j < CPT; j++) cm[j] = 0.f;
        for (int m = 0; m < MPG; m++) {
            int i = node0 + g * MPG + m;
            if (i >= N) break;
            int bg = batch[i];
            if (bg != curg) {
                if (curg >= 0) {
                    #pragma unroll
                    for (int j = 0; j < CPT; j++)
                        atomicMax(reinterpret_cast<int*>(&pooled[(size_t)curg * F + c + j * FC]),
                                  __float_as_int(cm[j]));
                }
                curg = bg;
                #pragma unroll
                for (int j = 0; j < CPT; j++) cm[j] = 0.f;
            }
            #pragma unroll
            for (int j = 0; j < CPT; j++)
                cm[j] = fmaxf(cm[j], fmaxf(acc[m][j], 0.f));
        }
        if (curg >= 0) {
            #pragma unroll
            for (int j = 0; j < CPT; j++)
                atomicMax(reinterpret_cast<int*>(&pooled[(size_t)curg * F + c + j * FC]),
                          __float_as_int(cm[j]));
        }
    } else {
        for (int m = 0; m < MPG; m++) {
            int i = node0 + g * MPG + m;
            if (i >= N) break;
            #pragma unroll
            for (int j = 0; j < CPT; j++)
                out[(size_t)i * F + c + j * FC] = fmaxf(acc[m][j], 0.f);
        }
    }
}

// ---------------- head: logits -> log_softmax, softmax ----------------

__global__ __launch_bounds__(320) void head_k(const float* __restrict__ pooled,
                                              const float* __restrict__ Wl,
                                              const float* __restrict__ bl,
                                              float* __restrict__ out) {
    __shared__ float lg[GG][10];
    __shared__ float lse[GG];
    int t = threadIdx.x;
    int g = t / 10, c = t % 10;
    float acc = bl[c];
    for (int k = 0; k < 256; k++) acc = fmaf(pooled[g * 256 + k], Wl[k * 10 + c], acc);
    lg[g][c] = acc;
    __syncthreads();
    if (c == 0) {
        float mx = -1e30f;
        for (int j = 0; j < 10; j++) mx = fmaxf(mx, lg[g][j]);
        float s = 0.f;
        for (int j = 0; j < 10; j++) s += expf(lg[g][j] - mx);
        lse[g] = mx + logf(s);
    }
    __syncthreads();
    float o = acc - lse[g];
    out[g * 10 + c] = o;             // log_softmax
    out[320 + g * 10 + c] = expf(o); // softmax(log_softmax(x)) == exp(log_softmax(x))
}

// ---------------- launch ----------------

extern "C" void kernel_launch(void* const* d_in, const int* in_sizes, int n_in,
                              void* d_out, int out_size, void* d_ws, size_t ws_size,
                              hipStream_t stream) {
    const int N = NN, E = EE;
    const float* nrm = (const float*)d_in[0];
    const float* pos = (const float*)d_in[1];
    const float* x   = (const float*)d_in[2];
    const int* ei    = (const int*)d_in[3];
    const int* batch = (const int*)d_in[4];
    const float* W1 = (const float*)d_in[5];
    const float* b1 = (const float*)d_in[6];
    const float* W2 = (const float*)d_in[7];
    const float* b2 = (const float*)d_in[8];
    const float* W3 = (const float*)d_in[9];
    const float* b3 = (const float*)d_in[10];
    const float* Wl = (const float*)d_in[11];
    const float* bl = (const float*)d_in[12];

    const int* esrc = ei;
    const int* edst = ei + E;

    char* w = (char*)d_ws;
    auto carve = [&](size_t bytes) {
        void* p = (void*)w;
        w += (bytes + 255) & ~(size_t)255;
        return p;
    };
    int* wp      = (int*)carve((size_t)N * 4);
    int* rowptr  = (int*)carve((size_t)(N + 1) * 4);
    int* col     = (int*)carve((size_t)E * 4);
    float* inp   = (float*)carve((size_t)N * 8 * 4);
    float* agg1  = (float*)carve((size_t)N * 8 * 4);
    float* aggh1 = (float*)carve((size_t)N * 64 * 4);
    float* h2    = (float*)carve((size_t)N * 128 * 4);
    float* aggh2 = (float*)carve((size_t)N * 128 * 4);
    float* h1    = aggh2; // alias: h1 dead before aggh2 is written
    float* W3p   = (float*)carve((size_t)200 * 256 * 4);
    float* pooled= (float*)carve((size_t)GG * 256 * 4);

    hipMemsetAsync(wp, 0, (size_t)N * 4, stream);
    hipMemsetAsync(pooled, 0, (size_t)GG * 256 * 4, stream);

    hist_k<<<(E + 255) / 256, 256, 0, stream>>>(edst, wp, E);
    scan_k<<<1, 1024, 0, stream>>>(wp, rowptr, N, E);
    scatter_k<<<(E + 255) / 256, 256, 0, stream>>>(esrc, edst, wp, col, E);

    build_inp<<<(N * 8 + 255) / 256, 256, 0, stream>>>(nrm, pos, x, inp, N);
    build_w3p<<<(200 * 256 + 255) / 256, 256, 0, stream>>>(W3, W3p);

    // layer 1: agg1 = A @ inp ; h1 = relu(agg1 @ W1 + b1)
    agg4_k<8><<<(N + 127) / 128, 256, 0, stream>>>(rowptr, col, inp, agg1, N);
    transform_k<8, 64, 16, 8, 1, 8, 0, 0, false><<<(N + 127) / 128, 512, 0, stream>>>(
        agg1, nullptr, nullptr, W1, b1, h1, nullptr, nullptr, N);

    // layer 2: aggh1 = A @ h1 ; h2 = relu([aggh1|agg1] @ W2 + b2)
    agg4_k<64><<<(N + 15) / 16, 256, 0, stream>>>(rowptr, col, h1, aggh1, N);
    transform_k<72, 128, 16, 8, 2, 64, 8, 0, false><<<(N + 127) / 128, 512, 0, stream>>>(
        aggh1, agg1, nullptr, W2, b2, h2, nullptr, nullptr, N);

    // layer 3: aggh2 = A @ h2 ; pooled = segmax(relu([aggh1|agg1|aggh2] @ W3' + b3))
    agg4_k<128><<<(N + 7) / 8, 256, 0, stream>>>(rowptr, col, h2, aggh2, N);
    transform_k<200, 256, 16, 4, 2, 64, 8, 128, true><<<(N + 63) / 64, 512, 0, stream>>>(
        aggh1, agg1, aggh2, W3p, b3, nullptr, batch, pooled, N);

    head_k<<<1, 320, 0, stream>>>(pooled, Wl, bl, (float*)d_out);
}

// Round 4
// 300.728 us; speedup vs baseline: 2.1049x; 1.2830x over previous
//
#include <hip/hip_runtime.h>
#include <hip/hip_bf16.h>

#define NN 50000
#define EE 800000
#define GG 32

using short8 = __attribute__((ext_vector_type(8))) short;
using f32x4  = __attribute__((ext_vector_type(4))) float;

__device__ __forceinline__ ushort f2bf(float f) {
    __hip_bfloat16 hb = __float2bfloat16(f);
    return *reinterpret_cast<ushort*>(&hb);
}

// ---------------- CSR build ----------------

__global__ void hist_k(const int* __restrict__ dst, int* __restrict__ cnt, int E) {
    int e = blockIdx.x * blockDim.x + threadIdx.x;
    if (e < E) atomicAdd(&cnt[dst[e]], 1);
}

__global__ void scan_k(int* __restrict__ cnt_wp, int* __restrict__ rowptr, int N, int E) {
    __shared__ int wsum[16];
    int tid = threadIdx.x;
    int lane = tid & 63;
    int w = tid >> 6;
    int carry = 0;
    for (int base = 0; base < N; base += 1024) {
        int i = base + tid;
        int v = (i < N) ? cnt_wp[i] : 0;
        int s = v;
        #pragma unroll
        for (int off = 1; off < 64; off <<= 1) {
            int t = __shfl_up(s, off, 64);
            if (lane >= off) s += t;
        }
        if (lane == 63) wsum[w] = s;
        __syncthreads();
        if (w == 0 && lane < 16) {
            int t = wsum[lane];
            #pragma unroll
            for (int off = 1; off < 16; off <<= 1) {
                int u = __shfl_up(t, off, 64);
                if (lane >= off) t += u;
            }
            wsum[lane] = t;
        }
        __syncthreads();
        int wbase = (w == 0) ? 0 : wsum[w - 1];
        int incl = carry + wbase + s;
        int excl = incl - v;
        if (i < N) { rowptr[i] = excl; cnt_wp[i] = excl; }
        carry += wsum[15];
        __syncthreads();
    }
    if (tid == 0) rowptr[N] = E;
}

__global__ void scatter_k(const int* __restrict__ src, const int* __restrict__ dst,
                          int* __restrict__ wp, int* __restrict__ col, int E) {
    int e = blockIdx.x * blockDim.x + threadIdx.x;
    if (e < E) {
        int p = atomicAdd(&wp[dst[e]], 1);
        col[p] = src[e];
    }
}

// graph start offsets from sorted batch
__global__ void gstart_k(const int* __restrict__ batch, int* __restrict__ gstart, int N) {
    int i = blockIdx.x * blockDim.x + threadIdx.x;
    if (i >= N) return;
    int b = batch[i];
    if (i == 0) { for (int g = 0; g <= b; g++) gstart[g] = 0; }
    else {
        int p = batch[i - 1];
        for (int g = p + 1; g <= b; g++) gstart[g] = i;
    }
    if (i == N - 1) { for (int g = b + 1; g <= GG; g++) gstart[g] = N; }
}

// ---------------- setup: inp (bf16) and transposed bf16 weights ----------------

__global__ void build_inp_bf(const float* __restrict__ nrm, const float* __restrict__ pos,
                             const float* __restrict__ x, ushort* __restrict__ inp, int N) {
    int i = blockIdx.x * blockDim.x + threadIdx.x;
    if (i >= N) return;
    float v[8];
    v[0] = nrm[i * 3]; v[1] = nrm[i * 3 + 1]; v[2] = nrm[i * 3 + 2];
    v[3] = pos[i * 3]; v[4] = pos[i * 3 + 1]; v[5] = pos[i * 3 + 2];
    v[6] = x[i * 2];   v[7] = x[i * 2 + 1];
    uint4 d;
    d.x = (uint)f2bf(v[0]) | ((uint)f2bf(v[1]) << 16);
    d.y = (uint)f2bf(v[2]) | ((uint)f2bf(v[3]) << 16);
    d.z = (uint)f2bf(v[4]) | ((uint)f2bf(v[5]) << 16);
    d.w = (uint)f2bf(v[6]) | ((uint)f2bf(v[7]) << 16);
    *reinterpret_cast<uint4*>(&inp[(size_t)i * 8]) = d;
}

// Wt[n][k] = W[k][n] (+ fold of W3 rows 200:208 into 64:72), zero-padded to KPAD, bf16
__global__ void wtp_k(const float* __restrict__ W, ushort* __restrict__ Wt,
                      int K, int F, int KPAD, int fold) {
    int idx = blockIdx.x * blockDim.x + threadIdx.x;
    if (idx >= F * KPAD) return;
    int n = idx / KPAD, k = idx - n * KPAD;
    float v = 0.f;
    if (k < K) {
        v = W[(size_t)k * F + n];
        if (fold && k >= 64 && k < 72) v += W[(size_t)(k + 136) * F + n];
    }
    Wt[idx] = f2bf(v);
}

// ---------------- aggregation (bf16 in, f32 acc, bf16 out) ----------------

__device__ __forceinline__ void acc8(uint4 v, float* a) {
    a[0] += __uint_as_float(v.x << 16); a[1] += __uint_as_float(v.x & 0xffff0000u);
    a[2] += __uint_as_float(v.y << 16); a[3] += __uint_as_float(v.y & 0xffff0000u);
    a[4] += __uint_as_float(v.z << 16); a[5] += __uint_as_float(v.z & 0xffff0000u);
    a[6] += __uint_as_float(v.w << 16); a[7] += __uint_as_float(v.w & 0xffff0000u);
}

template <int F>
__global__ __launch_bounds__(256) void aggb_k(const int* __restrict__ rowptr,
                                              const int* __restrict__ col,
                                              const ushort* __restrict__ src,
                                              ushort* __restrict__ dst, int N) {
    constexpr int TPN = F / 8;
    constexpr int Q = 256 / TPN;
    int i = blockIdx.x * Q + threadIdx.x / TPN;
    int f8 = (threadIdx.x % TPN) * 8;
    if (i >= N) return;
    int e0 = rowptr[i], e1 = rowptr[i + 1];
    float a[8] = {0, 0, 0, 0, 0, 0, 0, 0};
    float b[8] = {0, 0, 0, 0, 0, 0, 0, 0};
    int e = e0;
    for (; e + 1 < e1; e += 2) {
        int s0 = col[e], s1 = col[e + 1];
        uint4 v0 = *reinterpret_cast<const uint4*>(&src[(size_t)s0 * F + f8]);
        uint4 v1 = *reinterpret_cast<const uint4*>(&src[(size_t)s1 * F + f8]);
        acc8(v0, a); acc8(v1, b);
    }
    if (e < e1) {
        uint4 v0 = *reinterpret_cast<const uint4*>(&src[(size_t)col[e] * F + f8]);
        acc8(v0, a);
    }
    uint4 o;
    o.x = (uint)f2bf(a[0] + b[0]) | ((uint)f2bf(a[1] + b[1]) << 16);
    o.y = (uint)f2bf(a[2] + b[2]) | ((uint)f2bf(a[3] + b[3]) << 16);
    o.z = (uint)f2bf(a[4] + b[4]) | ((uint)f2bf(a[5] + b[5]) << 16);
    o.w = (uint)f2bf(a[6] + b[6]) | ((uint)f2bf(a[7] + b[7]) << 16);
    *reinterpret_cast<uint4*>(&dst[(size_t)i * F + f8]) = o;
}

// ---------------- MFMA dense transform ----------------
// out[N][F] = relu(concat(inA,inB,inC)[N][K] @ W[K][F] + b), all features bf16.
// Block: 256 threads = 4 waves; BM=64 rows (16 per wave); Wt is W transposed
// [F][KPAD] bf16 so B-fragments are contiguous dwordx4 from L2.
// Fragment layouts (m89/m91-verified): A/B lane l -> row l&15, k=(l>>4)*8+e;
// C/D: col=lane&15, row=(lane>>4)*4+reg.

template <int K, int KPAD, int LDA, int F, int WA, int WB, int WC>
__global__ __launch_bounds__(256) void mfma_transform_k(
        const ushort* __restrict__ inA, const ushort* __restrict__ inB,
        const ushort* __restrict__ inC, const ushort* __restrict__ Wt,
        const float* __restrict__ bias, ushort* __restrict__ out, int N) {
    constexpr int KS = KPAD / 32;
    constexpr int NT = F / 16;
    __shared__ ushort At[64 * LDA];
    const int node0 = blockIdx.x * 64;
    const int tid = threadIdx.x;
    const int lane = tid & 63;
    const int wv = tid >> 6;

    // ---- stage A rows into LDS as [64][LDA] (uint4 = 8 bf16 per move) ----
    {
        constexpr int NV = WA / 8;
        for (int idx = tid; idx < 64 * NV; idx += 256) {
            int m = idx / NV, q = idx - m * NV;
            int i = node0 + m;
            uint4 v = make_uint4(0, 0, 0, 0);
            if (i < N) v = *reinterpret_cast<const uint4*>(&inA[(size_t)i * WA + q * 8]);
            *reinterpret_cast<uint4*>(&At[m * LDA + q * 8]) = v;
        }
    }
    if constexpr (WB > 0) {
        constexpr int NV = WB / 8;
        for (int idx = tid; idx < 64 * NV; idx += 256) {
            int m = idx / NV, q = idx - m * NV;
            int i = node0 + m;
            uint4 v = make_uint4(0, 0, 0, 0);
            if (i < N) v = *reinterpret_cast<const uint4*>(&inB[(size_t)i * WB + q * 8]);
            *reinterpret_cast<uint4*>(&At[m * LDA + WA + q * 8]) = v;
        }
    }
    if constexpr (WC > 0) {
        constexpr int NV = WC / 8;
        for (int idx = tid; idx < 64 * NV; idx += 256) {
            int m = idx / NV, q = idx - m * NV;
            int i = node0 + m;
            uint4 v = make_uint4(0, 0, 0, 0);
            if (i < N) v = *reinterpret_cast<const uint4*>(&inC[(size_t)i * WC + q * 8]);
            *reinterpret_cast<uint4*>(&At[m * LDA + WA + WB + q * 8]) = v;
        }
    }
    {   // zero-pad k in [K, LDA)
        constexpr int PAD = LDA - K;
        for (int idx = tid; idx < 64 * PAD; idx += 256) {
            int m = idx / PAD, k = K + (idx - m * PAD);
            At[m * LDA + k] = 0;
        }
    }
    __syncthreads();

    f32x4 acc[NT];
    #pragma unroll
    for (int nt = 0; nt < NT; nt++) acc[nt] = (f32x4){0.f, 0.f, 0.f, 0.f};

    const int r15 = lane & 15, kg = lane >> 4;
    const ushort* arow = &At[(wv * 16 + r15) * LDA + kg * 8];
    #pragma unroll
    for (int kc = 0; kc < KS; kc++) {
        short8 a = *reinterpret_cast<const short8*>(arow + kc * 32);
        #pragma unroll
        for (int nt = 0; nt < NT; nt++) {
            short8 b = *reinterpret_cast<const short8*>(
                &Wt[(size_t)(nt * 16 + r15) * KPAD + kc * 32 + kg * 8]);
            acc[nt] = __builtin_amdgcn_mfma_f32_16x16x32_bf16(a, b, acc[nt], 0, 0, 0);
        }
    }

    #pragma unroll
    for (int nt = 0; nt < NT; nt++) {
        int colg = nt * 16 + r15;
        float bv = bias[colg];
        #pragma unroll
        for (int reg = 0; reg < 4; reg++) {
            int row = node0 + wv * 16 + kg * 4 + reg;
            if (row < N) {
                float v = fmaxf(acc[nt][reg] + bv, 0.f);
                out[(size_t)row * F + colg] = f2bf(v);
            }
        }
    }
}

// ---------------- pool: pooled[g][c] = max over rows of graph g ----------------

#define PSPLIT 8
__global__ __launch_bounds__(256) void pool_k(const ushort* __restrict__ h3,
                                              const int* __restrict__ gstart,
                                              float* __restrict__ pooled) {
    int g = blockIdx.x, sp = blockIdx.y, c = threadIdx.x;
    int i0 = gstart[g], i1 = gstart[g + 1];
    int len = i1 - i0;
    int per = (len + PSPLIT - 1) / PSPLIT;
    int s = i0 + sp * per;
    int e = min(s + per, i1);
    if (s >= e) return;
    float m0 = 0.f, m1 = 0.f, m2 = 0.f, m3 = 0.f; // relu outputs are >= 0
    int i = s;
    for (; i + 3 < e; i += 4) {
        m0 = fmaxf(m0, __uint_as_float((uint)h3[(size_t)i * 256 + c] << 16));
        m1 = fmaxf(m1, __uint_as_float((uint)h3[(size_t)(i + 1) * 256 + c] << 16));
        m2 = fmaxf(m2, __uint_as_float((uint)h3[(size_t)(i + 2) * 256 + c] << 16));
        m3 = fmaxf(m3, __uint_as_float((uint)h3[(size_t)(i + 3) * 256 + c] << 16));
    }
    for (; i < e; i++)
        m0 = fmaxf(m0, __uint_as_float((uint)h3[(size_t)i * 256 + c] << 16));
    float mm = fmaxf(fmaxf(m0, m1), fmaxf(m2, m3));
    atomicMax(reinterpret_cast<int*>(&pooled[g * 256 + c]), __float_as_int(mm));
}

// ---------------- head: logits -> log_softmax, softmax ----------------

__global__ __launch_bounds__(320) void head_k(const float* __restrict__ pooled,
                                              const float* __restrict__ Wl,
                                              const float* __restrict__ bl,
                                              float* __restrict__ out) {
    __shared__ float lg[GG][10];
    __shared__ float lse[GG];
    int t = threadIdx.x;
    int g = t / 10, c = t % 10;
    float acc = bl[c];
    for (int k = 0; k < 256; k++) acc = fmaf(pooled[g * 256 + k], Wl[k * 10 + c], acc);
    lg[g][c] = acc;
    __syncthreads();
    if (c == 0) {
        float mx = -1e30f;
        for (int j = 0; j < 10; j++) mx = fmaxf(mx, lg[g][j]);
        float s = 0.f;
        for (int j = 0; j < 10; j++) s += expf(lg[g][j] - mx);
        lse[g] = mx + logf(s);
    }
    __syncthreads();
    float o = acc - lse[g];
    out[g * 10 + c] = o;             // log_softmax
    out[320 + g * 10 + c] = expf(o); // softmax(log_softmax(x)) == exp(log_softmax(x))
}

// ---------------- launch ----------------

extern "C" void kernel_launch(void* const* d_in, const int* in_sizes, int n_in,
                              void* d_out, int out_size, void* d_ws, size_t ws_size,
                              hipStream_t stream) {
    const int N = NN, E = EE;
    const float* nrm = (const float*)d_in[0];
    const float* pos = (const float*)d_in[1];
    const float* x   = (const float*)d_in[2];
    const int* ei    = (const int*)d_in[3];
    const int* batch = (const int*)d_in[4];
    const float* W1 = (const float*)d_in[5];
    const float* b1 = (const float*)d_in[6];
    const float* W2 = (const float*)d_in[7];
    const float* b2 = (const float*)d_in[8];
    const float* W3 = (const float*)d_in[9];
    const float* b3 = (const float*)d_in[10];
    const float* Wl = (const float*)d_in[11];
    const float* bl = (const float*)d_in[12];

    const int* esrc = ei;
    const int* edst = ei + E;

    char* w = (char*)d_ws;
    auto carve = [&](size_t bytes) {
        void* p = (void*)w;
        w += (bytes + 255) & ~(size_t)255;
        return p;
    };
    int* wp       = (int*)carve((size_t)N * 4);
    int* rowptr   = (int*)carve((size_t)(N + 1) * 4);
    int* col      = (int*)carve((size_t)E * 4);
    int* gstart   = (int*)carve((size_t)(GG + 1) * 4);
    ushort* inpb  = (ushort*)carve((size_t)N * 8 * 2);
    ushort* agg1  = (ushort*)carve((size_t)N * 8 * 2);
    ushort* h1    = (ushort*)carve((size_t)N * 64 * 2);
    ushort* aggh1 = (ushort*)carve((size_t)N * 64 * 2);
    ushort* h2    = (ushort*)carve((size_t)N * 128 * 2);
    ushort* aggh2 = (ushort*)carve((size_t)N * 128 * 2);
    ushort* h3    = (ushort*)carve((size_t)N * 256 * 2);
    ushort* Wt1   = (ushort*)carve((size_t)64 * 32 * 2);
    ushort* Wt2   = (ushort*)carve((size_t)128 * 96 * 2);
    ushort* Wt3   = (ushort*)carve((size_t)256 * 224 * 2);
    float* pooled = (float*)carve((size_t)GG * 256 * 4);

    hipMemsetAsync(wp, 0, (size_t)N * 4, stream);
    hipMemsetAsync(pooled, 0, (size_t)GG * 256 * 4, stream);

    hist_k<<<(E + 255) / 256, 256, 0, stream>>>(edst, wp, E);
    scan_k<<<1, 1024, 0, stream>>>(wp, rowptr, N, E);
    scatter_k<<<(E + 255) / 256, 256, 0, stream>>>(esrc, edst, wp, col, E);

    build_inp_bf<<<(N + 255) / 256, 256, 0, stream>>>(nrm, pos, x, inpb, N);
    gstart_k<<<(N + 255) / 256, 256, 0, stream>>>(batch, gstart, N);
    wtp_k<<<(64 * 32 + 255) / 256, 256, 0, stream>>>(W1, Wt1, 8, 64, 32, 0);
    wtp_k<<<(128 * 96 + 255) / 256, 256, 0, stream>>>(W2, Wt2, 72, 128, 96, 0);
    wtp_k<<<(256 * 224 + 255) / 256, 256, 0, stream>>>(W3, Wt3, 200, 256, 224, 1);

    // layer 1
    aggb_k<8><<<(N + 255) / 256, 256, 0, stream>>>(rowptr, col, inpb, agg1, N);
    mfma_transform_k<8, 32, 40, 64, 8, 0, 0><<<(N + 63) / 64, 256, 0, stream>>>(
        agg1, nullptr, nullptr, Wt1, b1, h1, N);

    // layer 2
    aggb_k<64><<<(N + 31) / 32, 256, 0, stream>>>(rowptr, col, h1, aggh1, N);
    mfma_transform_k<72, 96, 104, 128, 64, 8, 0><<<(N + 63) / 64, 256, 0, stream>>>(
        aggh1, agg1, nullptr, Wt2, b2, h2, N);

    // layer 3
    aggb_k<128><<<(N + 15) / 16, 256, 0, stream>>>(rowptr, col, h2, aggh2, N);
    mfma_transform_k<200, 224, 232, 256, 64, 8, 128><<<(N + 63) / 64, 256, 0, stream>>>(
        aggh1, agg1, aggh2, Wt3, b3, h3, N);

    // pool + head
    pool_k<<<dim3(GG, PSPLIT), 256, 0, stream>>>(h3, gstart, pooled);
    head_k<<<1, 320, 0, stream>>>(pooled, Wl, bl, (float*)d_out);
}

// Round 5
// 288.271 us; speedup vs baseline: 2.1958x; 1.0432x over previous
//
#include <hip/hip_runtime.h>
#include <hip/hip_bf16.h>

#define NN 50000
#define EE 800000
#define GG 32

using short8 = __attribute__((ext_vector_type(8))) short;
using f32x4  = __attribute__((ext_vector_type(4))) float;

__device__ __forceinline__ ushort f2bf(float f) {
    __hip_bfloat16 hb = __float2bfloat16(f);
    return *reinterpret_cast<ushort*>(&hb);
}

// ---------------- CSR build ----------------

__global__ void hist_k(const int* __restrict__ dst, int* __restrict__ cnt, int E) {
    int e = blockIdx.x * blockDim.x + threadIdx.x;
    if (e < E) atomicAdd(&cnt[dst[e]], 1);
}

__global__ void scan_k(int* __restrict__ cnt_wp, int* __restrict__ rowptr, int N, int E) {
    __shared__ int wsum[16];
    int tid = threadIdx.x;
    int lane = tid & 63;
    int w = tid >> 6;
    int carry = 0;
    for (int base = 0; base < N; base += 1024) {
        int i = base + tid;
        int v = (i < N) ? cnt_wp[i] : 0;
        int s = v;
        #pragma unroll
        for (int off = 1; off < 64; off <<= 1) {
            int t = __shfl_up(s, off, 64);
            if (lane >= off) s += t;
        }
        if (lane == 63) wsum[w] = s;
        __syncthreads();
        if (w == 0 && lane < 16) {
            int t = wsum[lane];
            #pragma unroll
            for (int off = 1; off < 16; off <<= 1) {
                int u = __shfl_up(t, off, 64);
                if (lane >= off) t += u;
            }
            wsum[lane] = t;
        }
        __syncthreads();
        int wbase = (w == 0) ? 0 : wsum[w - 1];
        int incl = carry + wbase + s;
        int excl = incl - v;
        if (i < N) { rowptr[i] = excl; cnt_wp[i] = excl; }
        carry += wsum[15];
        __syncthreads();
    }
    if (tid == 0) rowptr[N] = E;
}

__global__ void scatter_k(const int* __restrict__ src, const int* __restrict__ dst,
                          int* __restrict__ wp, int* __restrict__ col, int E) {
    int e = blockIdx.x * blockDim.x + threadIdx.x;
    if (e < E) {
        int p = atomicAdd(&wp[dst[e]], 1);
        col[p] = src[e];
    }
}

// graph start offsets from sorted batch
__global__ void gstart_k(const int* __restrict__ batch, int* __restrict__ gstart, int N) {
    int i = blockIdx.x * blockDim.x + threadIdx.x;
    if (i >= N) return;
    int b = batch[i];
    if (i == 0) { for (int g = 0; g <= b; g++) gstart[g] = 0; }
    else {
        int p = batch[i - 1];
        for (int g = p + 1; g <= b; g++) gstart[g] = i;
    }
    if (i == N - 1) { for (int g = b + 1; g <= GG; g++) gstart[g] = N; }
}

// ---------------- setup: inp (bf16) and transposed bf16 weights ----------------

__global__ void build_inp_bf(const float* __restrict__ nrm, const float* __restrict__ pos,
                             const float* __restrict__ x, ushort* __restrict__ inp, int N) {
    int i = blockIdx.x * blockDim.x + threadIdx.x;
    if (i >= N) return;
    float v[8];
    v[0] = nrm[i * 3]; v[1] = nrm[i * 3 + 1]; v[2] = nrm[i * 3 + 2];
    v[3] = pos[i * 3]; v[4] = pos[i * 3 + 1]; v[5] = pos[i * 3 + 2];
    v[6] = x[i * 2];   v[7] = x[i * 2 + 1];
    uint4 d;
    d.x = (uint)f2bf(v[0]) | ((uint)f2bf(v[1]) << 16);
    d.y = (uint)f2bf(v[2]) | ((uint)f2bf(v[3]) << 16);
    d.z = (uint)f2bf(v[4]) | ((uint)f2bf(v[5]) << 16);
    d.w = (uint)f2bf(v[6]) | ((uint)f2bf(v[7]) << 16);
    *reinterpret_cast<uint4*>(&inp[(size_t)i * 8]) = d;
}

// Wt[n][k] = W[k][n] (+ fold of W3 rows 200:208 into 64:72), zero-padded to KPAD, bf16
__global__ void wtp_k(const float* __restrict__ W, ushort* __restrict__ Wt,
                      int K, int F, int KPAD, int fold) {
    int idx = blockIdx.x * blockDim.x + threadIdx.x;
    if (idx >= F * KPAD) return;
    int n = idx / KPAD, k = idx - n * KPAD;
    float v = 0.f;
    if (k < K) {
        v = W[(size_t)k * F + n];
        if (fold && k >= 64 && k < 72) v += W[(size_t)(k + 136) * F + n];
    }
    Wt[idx] = f2bf(v);
}

// ---------------- aggregation (bf16 in, f32 acc, bf16 out) ----------------
// 4 independent gather chains per thread for memory-latency hiding.

__device__ __forceinline__ void acc8(uint4 v, float* a) {
    a[0] += __uint_as_float(v.x << 16); a[1] += __uint_as_float(v.x & 0xffff0000u);
    a[2] += __uint_as_float(v.y << 16); a[3] += __uint_as_float(v.y & 0xffff0000u);
    a[4] += __uint_as_float(v.z << 16); a[5] += __uint_as_float(v.z & 0xffff0000u);
    a[6] += __uint_as_float(v.w << 16); a[7] += __uint_as_float(v.w & 0xffff0000u);
}

template <int F>
__global__ __launch_bounds__(256, 6) void aggb_k(const int* __restrict__ rowptr,
                                                 const int* __restrict__ col,
                                                 const ushort* __restrict__ src,
                                                 ushort* __restrict__ dst, int N) {
    constexpr int TPN = F / 8;
    constexpr int Q = 256 / TPN;
    int i = blockIdx.x * Q + threadIdx.x / TPN;
    int f8 = (threadIdx.x % TPN) * 8;
    if (i >= N) return;
    int e0 = rowptr[i], e1 = rowptr[i + 1];
    float a0[8] = {0,0,0,0,0,0,0,0};
    float a1[8] = {0,0,0,0,0,0,0,0};
    float a2[8] = {0,0,0,0,0,0,0,0};
    float a3[8] = {0,0,0,0,0,0,0,0};
    int e = e0;
    for (; e + 3 < e1; e += 4) {
        int s0 = col[e], s1 = col[e + 1], s2 = col[e + 2], s3 = col[e + 3];
        uint4 v0 = *reinterpret_cast<const uint4*>(&src[(size_t)s0 * F + f8]);
        uint4 v1 = *reinterpret_cast<const uint4*>(&src[(size_t)s1 * F + f8]);
        uint4 v2 = *reinterpret_cast<const uint4*>(&src[(size_t)s2 * F + f8]);
        uint4 v3 = *reinterpret_cast<const uint4*>(&src[(size_t)s3 * F + f8]);
        acc8(v0, a0); acc8(v1, a1); acc8(v2, a2); acc8(v3, a3);
    }
    for (; e < e1; e++) {
        uint4 v0 = *reinterpret_cast<const uint4*>(&src[(size_t)col[e] * F + f8]);
        acc8(v0, a0);
    }
    uint4 o;
    o.x = (uint)f2bf(a0[0]+a1[0]+a2[0]+a3[0]) | ((uint)f2bf(a0[1]+a1[1]+a2[1]+a3[1]) << 16);
    o.y = (uint)f2bf(a0[2]+a1[2]+a2[2]+a3[2]) | ((uint)f2bf(a0[3]+a1[3]+a2[3]+a3[3]) << 16);
    o.z = (uint)f2bf(a0[4]+a1[4]+a2[4]+a3[4]) | ((uint)f2bf(a0[5]+a1[5]+a2[5]+a3[5]) << 16);
    o.w = (uint)f2bf(a0[6]+a1[6]+a2[6]+a3[6]) | ((uint)f2bf(a0[7]+a1[7]+a2[7]+a3[7]) << 16);
    *reinterpret_cast<uint4*>(&dst[(size_t)i * F + f8]) = o;
}

// ---------------- MFMA dense transform ----------------
// out[N][F] = relu(concat(inA,inB,inC)[N][K] @ W[K][F] + b), all features bf16.
// 512 threads = 8 waves in a 4(M) x 2(N) wave grid over BM=64 rows;
// each wave: 16 rows x F/2 cols. k-loop fully unrolled so the compiler can
// keep many independent Wt (L2) loads in flight per wave (latency hiding).
// Fragment layouts (m89/m91-verified): A/B lane l -> row l&15, k=(l>>4)*8+e;
// C/D: col=lane&15, row=(lane>>4)*4+reg.

template <int K, int KPAD, int LDA, int F, int WA, int WB, int WC>
__global__ __launch_bounds__(512, 4) void mfma_transform_k(
        const ushort* __restrict__ inA, const ushort* __restrict__ inB,
        const ushort* __restrict__ inC, const ushort* __restrict__ Wt,
        const float* __restrict__ bias, ushort* __restrict__ out, int N) {
    constexpr int KS = KPAD / 32;
    constexpr int NWN = 2;                 // wave grid: 4 (M) x 2 (N)
    constexpr int FW = F / NWN;            // cols per wave
    constexpr int NT = FW / 16;            // 16-col tiles per wave
    __shared__ ushort At[64 * LDA];
    const int node0 = blockIdx.x * 64;
    const int tid = threadIdx.x;
    const int lane = tid & 63;
    const int wv = tid >> 6;
    const int wm = wv & 3;                 // M-strip (16 rows)
    const int wn = wv >> 2;                // N-half

    // ---- stage A rows into LDS as [64][LDA] (uint4 = 8 bf16 per move) ----
    {
        constexpr int NV = WA / 8;
        for (int idx = tid; idx < 64 * NV; idx += 512) {
            int m = idx / NV, q = idx - m * NV;
            int i = node0 + m;
            uint4 v = make_uint4(0, 0, 0, 0);
            if (i < N) v = *reinterpret_cast<const uint4*>(&inA[(size_t)i * WA + q * 8]);
            *reinterpret_cast<uint4*>(&At[m * LDA + q * 8]) = v;
        }
    }
    if constexpr (WB > 0) {
        constexpr int NV = WB / 8;
        for (int idx = tid; idx < 64 * NV; idx += 512) {
            int m = idx / NV, q = idx - m * NV;
            int i = node0 + m;
            uint4 v = make_uint4(0, 0, 0, 0);
            if (i < N) v = *reinterpret_cast<const uint4*>(&inB[(size_t)i * WB + q * 8]);
            *reinterpret_cast<uint4*>(&At[m * LDA + WA + q * 8]) = v;
        }
    }
    if constexpr (WC > 0) {
        constexpr int NV = WC / 8;
        for (int idx = tid; idx < 64 * NV; idx += 512) {
            int m = idx / NV, q = idx - m * NV;
            int i = node0 + m;
            uint4 v = make_uint4(0, 0, 0, 0);
            if (i < N) v = *reinterpret_cast<const uint4*>(&inC[(size_t)i * WC + q * 8]);
            *reinterpret_cast<uint4*>(&At[m * LDA + WA + WB + q * 8]) = v;
        }
    }
    {   // zero-pad k in [K, LDA)
        constexpr int PAD = LDA - K;
        for (int idx = tid; idx < 64 * PAD; idx += 512) {
            int m = idx / PAD, k = K + (idx - m * PAD);
            At[m * LDA + k] = 0;
        }
    }
    __syncthreads();

    f32x4 acc[NT];
    #pragma unroll
    for (int nt = 0; nt < NT; nt++) acc[nt] = (f32x4){0.f, 0.f, 0.f, 0.f};

    const int r15 = lane & 15, kg = lane >> 4;
    const ushort* arow = &At[(wm * 16 + r15) * LDA + kg * 8];
    const ushort* wbase = &Wt[(size_t)(wn * FW + r15) * KPAD + kg * 8];
    #pragma unroll
    for (int kc = 0; kc < KS; kc++) {
        short8 a = *reinterpret_cast<const short8*>(arow + kc * 32);
        #pragma unroll
        for (int nt = 0; nt < NT; nt++) {
            short8 b = *reinterpret_cast<const short8*>(
                wbase + (size_t)nt * 16 * KPAD + kc * 32);
            acc[nt] = __builtin_amdgcn_mfma_f32_16x16x32_bf16(a, b, acc[nt], 0, 0, 0);
        }
    }

    #pragma unroll
    for (int nt = 0; nt < NT; nt++) {
        int colg = wn * FW + nt * 16 + r15;
        float bv = bias[colg];
        #pragma unroll
        for (int reg = 0; reg < 4; reg++) {
            int row = node0 + wm * 16 + kg * 4 + reg;
            if (row < N) {
                float v = fmaxf(acc[nt][reg] + bv, 0.f);
                out[(size_t)row * F + colg] = f2bf(v);
            }
        }
    }
}

// ---------------- pool: pooled[g][c] = max over rows of graph g ----------------

#define PSPLIT 8
__global__ __launch_bounds__(256) void pool_k(const ushort* __restrict__ h3,
                                              const int* __restrict__ gstart,
                                              float* __restrict__ pooled) {
    int g = blockIdx.x, sp = blockIdx.y, c = threadIdx.x;
    int i0 = gstart[g], i1 = gstart[g + 1];
    int len = i1 - i0;
    int per = (len + PSPLIT - 1) / PSPLIT;
    int s = i0 + sp * per;
    int e = min(s + per, i1);
    if (s >= e) return;
    float m0 = 0.f, m1 = 0.f, m2 = 0.f, m3 = 0.f; // relu outputs are >= 0
    int i = s;
    for (; i + 3 < e; i += 4) {
        m0 = fmaxf(m0, __uint_as_float((uint)h3[(size_t)i * 256 + c] << 16));
        m1 = fmaxf(m1, __uint_as_float((uint)h3[(size_t)(i + 1) * 256 + c] << 16));
        m2 = fmaxf(m2, __uint_as_float((uint)h3[(size_t)(i + 2) * 256 + c] << 16));
        m3 = fmaxf(m3, __uint_as_float((uint)h3[(size_t)(i + 3) * 256 + c] << 16));
    }
    for (; i < e; i++)
        m0 = fmaxf(m0, __uint_as_float((uint)h3[(size_t)i * 256 + c] << 16));
    float mm = fmaxf(fmaxf(m0, m1), fmaxf(m2, m3));
    atomicMax(reinterpret_cast<int*>(&pooled[g * 256 + c]), __float_as_int(mm));
}

// ---------------- head: logits -> log_softmax, softmax ----------------

__global__ __launch_bounds__(320) void head_k(const float* __restrict__ pooled,
                                              const float* __restrict__ Wl,
                                              const float* __restrict__ bl,
                                              float* __restrict__ out) {
    __shared__ float lg[GG][10];
    __shared__ float lse[GG];
    int t = threadIdx.x;
    int g = t / 10, c = t % 10;
    float acc = bl[c];
    for (int k = 0; k < 256; k++) acc = fmaf(pooled[g * 256 + k], Wl[k * 10 + c], acc);
    lg[g][c] = acc;
    __syncthreads();
    if (c == 0) {
        float mx = -1e30f;
        for (int j = 0; j < 10; j++) mx = fmaxf(mx, lg[g][j]);
        float s = 0.f;
        for (int j = 0; j < 10; j++) s += expf(lg[g][j] - mx);
        lse[g] = mx + logf(s);
    }
    __syncthreads();
    float o = acc - lse[g];
    out[g * 10 + c] = o;             // log_softmax
    out[320 + g * 10 + c] = expf(o); // softmax(log_softmax(x)) == exp(log_softmax(x))
}

// ---------------- launch ----------------

extern "C" void kernel_launch(void* const* d_in, const int* in_sizes, int n_in,
                              void* d_out, int out_size, void* d_ws, size_t ws_size,
                              hipStream_t stream) {
    const int N = NN, E = EE;
    const float* nrm = (const float*)d_in[0];
    const float* pos = (const float*)d_in[1];
    const float* x   = (const float*)d_in[2];
    const int* ei    = (const int*)d_in[3];
    const int* batch = (const int*)d_in[4];
    const float* W1 = (const float*)d_in[5];
    const float* b1 = (const float*)d_in[6];
    const float* W2 = (const float*)d_in[7];
    const float* b2 = (const float*)d_in[8];
    const float* W3 = (const float*)d_in[9];
    const float* b3 = (const float*)d_in[10];
    const float* Wl = (const float*)d_in[11];
    const float* bl = (const float*)d_in[12];

    const int* esrc = ei;
    const int* edst = ei + E;

    char* w = (char*)d_ws;
    auto carve = [&](size_t bytes) {
        void* p = (void*)w;
        w += (bytes + 255) & ~(size_t)255;
        return p;
    };
    int* wp       = (int*)carve((size_t)N * 4);
    int* rowptr   = (int*)carve((size_t)(N + 1) * 4);
    int* col      = (int*)carve((size_t)E * 4);
    int* gstart   = (int*)carve((size_t)(GG + 1) * 4);
    ushort* inpb  = (ushort*)carve((size_t)N * 8 * 2);
    ushort* agg1  = (ushort*)carve((size_t)N * 8 * 2);
    ushort* h1    = (ushort*)carve((size_t)N * 64 * 2);
    ushort* aggh1 = (ushort*)carve((size_t)N * 64 * 2);
    ushort* h2    = (ushort*)carve((size_t)N * 128 * 2);
    ushort* aggh2 = (ushort*)carve((size_t)N * 128 * 2);
    ushort* h3    = (ushort*)carve((size_t)N * 256 * 2);
    ushort* Wt1   = (ushort*)carve((size_t)64 * 32 * 2);
    ushort* Wt2   = (ushort*)carve((size_t)128 * 96 * 2);
    ushort* Wt3   = (ushort*)carve((size_t)256 * 224 * 2);
    float* pooled = (float*)carve((size_t)GG * 256 * 4);

    hipMemsetAsync(wp, 0, (size_t)N * 4, stream);
    hipMemsetAsync(pooled, 0, (size_t)GG * 256 * 4, stream);

    hist_k<<<(E + 255) / 256, 256, 0, stream>>>(edst, wp, E);
    scan_k<<<1, 1024, 0, stream>>>(wp, rowptr, N, E);
    scatter_k<<<(E + 255) / 256, 256, 0, stream>>>(esrc, edst, wp, col, E);

    build_inp_bf<<<(N + 255) / 256, 256, 0, stream>>>(nrm, pos, x, inpb, N);
    gstart_k<<<(N + 255) / 256, 256, 0, stream>>>(batch, gstart, N);
    wtp_k<<<(64 * 32 + 255) / 256, 256, 0, stream>>>(W1, Wt1, 8, 64, 32, 0);
    wtp_k<<<(128 * 96 + 255) / 256, 256, 0, stream>>>(W2, Wt2, 72, 128, 96, 0);
    wtp_k<<<(256 * 224 + 255) / 256, 256, 0, stream>>>(W3, Wt3, 200, 256, 224, 1);

    // layer 1
    aggb_k<8><<<(N + 255) / 256, 256, 0, stream>>>(rowptr, col, inpb, agg1, N);
    mfma_transform_k<8, 32, 40, 64, 8, 0, 0><<<(N + 63) / 64, 512, 0, stream>>>(
        agg1, nullptr, nullptr, Wt1, b1, h1, N);

    // layer 2
    aggb_k<64><<<(N + 31) / 32, 256, 0, stream>>>(rowptr, col, h1, aggh1, N);
    mfma_transform_k<72, 96, 104, 128, 64, 8, 0><<<(N + 63) / 64, 512, 0, stream>>>(
        aggh1, agg1, nullptr, Wt2, b2, h2, N);

    // layer 3
    aggb_k<128><<<(N + 15) / 16, 256, 0, stream>>>(rowptr, col, h2, aggh2, N);
    mfma_transform_k<200, 224, 232, 256, 64, 8, 128><<<(N + 63) / 64, 512, 0, stream>>>(
        aggh1, agg1, aggh2, Wt3, b3, h3, N);

    // pool + head
    pool_k<<<dim3(GG, PSPLIT), 256, 0, stream>>>(h3, gstart, pooled);
    head_k<<<1, 320, 0, stream>>>(pooled, Wl, bl, (float*)d_out);
}

// Round 6
// 251.746 us; speedup vs baseline: 2.5144x; 1.1451x over previous
//
#include <hip/hip_runtime.h>
#include <hip/hip_bf16.h>

#define NN 50000
#define EE 800000
#define GG 32
#define SCB 512                      // scan elements per block
#define NB ((NN + SCB - 1) / SCB)    // 98 scan blocks

using short8 = __attribute__((ext_vector_type(8))) short;
using f32x4  = __attribute__((ext_vector_type(4))) float;

__device__ __forceinline__ ushort f2bf(float f) {
    __hip_bfloat16 hb = __float2bfloat16(f);
    return *reinterpret_cast<ushort*>(&hb);
}

// ---------------- CSR build ----------------

__global__ void hist_k(const int* __restrict__ dst, int* __restrict__ cnt, int E) {
    int e = blockIdx.x * blockDim.x + threadIdx.x;
    if (e < E) atomicAdd(&cnt[dst[e]], 1);
}

// phase 1: per-block sums of cnt
__global__ __launch_bounds__(SCB) void scan1_k(const int* __restrict__ cnt,
                                               int* __restrict__ bsum, int N) {
    __shared__ int ws[SCB / 64];
    int tid = threadIdx.x, lane = tid & 63, w = tid >> 6;
    int i = blockIdx.x * SCB + tid;
    int s = (i < N) ? cnt[i] : 0;
    #pragma unroll
    for (int off = 32; off >= 1; off >>= 1) s += __shfl_down(s, off, 64);
    if (lane == 0) ws[w] = s;
    __syncthreads();
    if (tid == 0) {
        int t = 0;
        #pragma unroll
        for (int j = 0; j < SCB / 64; j++) t += ws[j];
        bsum[blockIdx.x] = t;
    }
}

// phase 2: exclusive scan of the NB block sums (single wave), rowptr[N]=E
__global__ __launch_bounds__(64) void scan2_k(int* __restrict__ bsum,
                                              int* __restrict__ rowptr, int nb, int E) {
    int lane = threadIdx.x;
    int carry = 0;
    for (int base = 0; base < nb; base += 64) {
        int v = (base + lane < nb) ? bsum[base + lane] : 0;
        int s = v;
        #pragma unroll
        for (int off = 1; off < 64; off <<= 1) {
            int t = __shfl_up(s, off, 64);
            if (lane >= off) s += t;
        }
        if (base + lane < nb) bsum[base + lane] = carry + s - v;
        carry += __shfl(s, 63, 64);
    }
    if (lane == 0) rowptr[NN] = E;
}

// phase 3: per-block exclusive scan + block offset -> rowptr & wp
__global__ __launch_bounds__(SCB) void scan3_k(const int* __restrict__ cnt,
                                               const int* __restrict__ bsum,
                                               int* __restrict__ rowptr,
                                               int* __restrict__ wp, int N) {
    __shared__ int ws[SCB / 64];
    int tid = threadIdx.x, lane = tid & 63, w = tid >> 6;
    int i = blockIdx.x * SCB + tid;
    int v = (i < N) ? cnt[i] : 0;
    int s = v;
    #pragma unroll
    for (int off = 1; off < 64; off <<= 1) {
        int t = __shfl_up(s, off, 64);
        if (lane >= off) s += t;
    }
    if (lane == 63) ws[w] = s;
    __syncthreads();
    if (w == 0 && lane < SCB / 64) {
        int t = ws[lane];
        #pragma unroll
        for (int off = 1; off < SCB / 64; off <<= 1) {
            int u = __shfl_up(t, off, 64);
            if (lane >= off) t += u;
        }
        ws[lane] = t;
    }
    __syncthreads();
    int excl = (w ? ws[w - 1] : 0) + s - v + bsum[blockIdx.x];
    if (i < N) { rowptr[i] = excl; wp[i] = excl; }
}

__global__ void scatter_k(const int* __restrict__ src, const int* __restrict__ dst,
                          int* __restrict__ wp, ushort* __restrict__ col, int E) {
    int e = blockIdx.x * blockDim.x + threadIdx.x;
    if (e < E) {
        int p = atomicAdd(&wp[dst[e]], 1);
        col[p] = (ushort)src[e];
    }
}

// ---------------- setup: inp (bf16) + graph starts ----------------

__global__ void prep_k(const float* __restrict__ nrm, const float* __restrict__ pos,
                       const float* __restrict__ x, const int* __restrict__ batch,
                       ushort* __restrict__ inp, int* __restrict__ gstart, int N) {
    int i = blockIdx.x * blockDim.x + threadIdx.x;
    if (i >= N) return;
    float v[8];
    v[0] = nrm[i * 3]; v[1] = nrm[i * 3 + 1]; v[2] = nrm[i * 3 + 2];
    v[3] = pos[i * 3]; v[4] = pos[i * 3 + 1]; v[5] = pos[i * 3 + 2];
    v[6] = x[i * 2];   v[7] = x[i * 2 + 1];
    uint4 d;
    d.x = (uint)f2bf(v[0]) | ((uint)f2bf(v[1]) << 16);
    d.y = (uint)f2bf(v[2]) | ((uint)f2bf(v[3]) << 16);
    d.z = (uint)f2bf(v[4]) | ((uint)f2bf(v[5]) << 16);
    d.w = (uint)f2bf(v[6]) | ((uint)f2bf(v[7]) << 16);
    *reinterpret_cast<uint4*>(&inp[(size_t)i * 8]) = d;

    int b = batch[i];
    if (i == 0) { for (int g = 0; g <= b; g++) gstart[g] = 0; }
    else {
        int p = batch[i - 1];
        for (int g = p + 1; g <= b; g++) gstart[g] = i;
    }
    if (i == N - 1) { for (int g = b + 1; g <= GG; g++) gstart[g] = N; }
}

// ---------------- transposed bf16 weights (all three in one kernel) ----------------
// Wt[n][k] = W[k][n] (+ fold of W3 rows 200:208 into 64:72), zero-padded to KPAD.

__device__ __forceinline__ void wtp_one(const float* W, ushort* Wt, int K, int F,
                                        int KPAD, int fold, int idx) {
    int n = idx / KPAD, k = idx - n * KPAD;
    float v = 0.f;
    if (k < K) {
        v = W[(size_t)k * F + n];
        if (fold && k >= 64 && k < 72) v += W[(size_t)(k + 136) * F + n];
    }
    Wt[idx] = f2bf(v);
}

__global__ void wtp_all_k(const float* __restrict__ W1, ushort* __restrict__ Wt1,
                          const float* __restrict__ W2, ushort* __restrict__ Wt2,
                          const float* __restrict__ W3, ushort* __restrict__ Wt3) {
    const int S1 = 64 * 32, S2 = 128 * 96, S3 = 256 * 224;
    int idx = blockIdx.x * blockDim.x + threadIdx.x;
    if (idx < S1) { wtp_one(W1, Wt1, 8, 64, 32, 0, idx); return; }
    idx -= S1;
    if (idx < S2) { wtp_one(W2, Wt2, 72, 128, 96, 0, idx); return; }
    idx -= S2;
    if (idx < S3) wtp_one(W3, Wt3, 200, 256, 224, 1, idx);
}

// ---------------- aggregation (bf16 in, f32 acc, bf16 out) ----------------

__device__ __forceinline__ void acc8(uint4 v, float* a) {
    a[0] += __uint_as_float(v.x << 16); a[1] += __uint_as_float(v.x & 0xffff0000u);
    a[2] += __uint_as_float(v.y << 16); a[3] += __uint_as_float(v.y & 0xffff0000u);
    a[4] += __uint_as_float(v.z << 16); a[5] += __uint_as_float(v.z & 0xffff0000u);
    a[6] += __uint_as_float(v.w << 16); a[7] += __uint_as_float(v.w & 0xffff0000u);
}

template <int F>
__global__ __launch_bounds__(256, 6) void aggb_k(const int* __restrict__ rowptr,
                                                 const ushort* __restrict__ col,
                                                 const ushort* __restrict__ src,
                                                 ushort* __restrict__ dst, int N) {
    constexpr int TPN = F / 8;
    constexpr int Q = 256 / TPN;
    int i = blockIdx.x * Q + threadIdx.x / TPN;
    int f8 = (threadIdx.x % TPN) * 8;
    if (i >= N) return;
    int e0 = rowptr[i], e1 = rowptr[i + 1];
    float a0[8] = {0,0,0,0,0,0,0,0};
    float a1[8] = {0,0,0,0,0,0,0,0};
    float a2[8] = {0,0,0,0,0,0,0,0};
    float a3[8] = {0,0,0,0,0,0,0,0};
    int e = e0;
    for (; e + 3 < e1; e += 4) {
        int s0 = col[e], s1 = col[e + 1], s2 = col[e + 2], s3 = col[e + 3];
        uint4 v0 = *reinterpret_cast<const uint4*>(&src[(size_t)s0 * F + f8]);
        uint4 v1 = *reinterpret_cast<const uint4*>(&src[(size_t)s1 * F + f8]);
        uint4 v2 = *reinterpret_cast<const uint4*>(&src[(size_t)s2 * F + f8]);
        uint4 v3 = *reinterpret_cast<const uint4*>(&src[(size_t)s3 * F + f8]);
        acc8(v0, a0); acc8(v1, a1); acc8(v2, a2); acc8(v3, a3);
    }
    for (; e < e1; e++) {
        uint4 v0 = *reinterpret_cast<const uint4*>(&src[(size_t)col[e] * F + f8]);
        acc8(v0, a0);
    }
    uint4 o;
    o.x = (uint)f2bf(a0[0]+a1[0]+a2[0]+a3[0]) | ((uint)f2bf(a0[1]+a1[1]+a2[1]+a3[1]) << 16);
    o.y = (uint)f2bf(a0[2]+a1[2]+a2[2]+a3[2]) | ((uint)f2bf(a0[3]+a1[3]+a2[3]+a3[3]) << 16);
    o.z = (uint)f2bf(a0[4]+a1[4]+a2[4]+a3[4]) | ((uint)f2bf(a0[5]+a1[5]+a2[5]+a3[5]) << 16);
    o.w = (uint)f2bf(a0[6]+a1[6]+a2[6]+a3[6]) | ((uint)f2bf(a0[7]+a1[7]+a2[7]+a3[7]) << 16);
    *reinterpret_cast<uint4*>(&dst[(size_t)i * F + f8]) = o;
}

// ---------------- MFMA dense transform ----------------
// out[N][F] = relu(concat(inA,inB,inC)[N][K] @ W[K][F] + b), all features bf16.
// 512 threads = 8 waves in a 4(M) x 2(N) wave grid over BM=64 rows; k-loop
// fully unrolled so many independent Wt (L2) loads stay in flight.
// Fragment layouts (m89/m91-verified): A/B lane l -> row l&15, k=(l>>4)*8+e;
// C/D: col=lane&15, row=(lane>>4)*4+reg.

template <int K, int KPAD, int LDA, int F, int WA, int WB, int WC>
__global__ __launch_bounds__(512, 4) void mfma_transform_k(
        const ushort* __restrict__ inA, const ushort* __restrict__ inB,
        const ushort* __restrict__ inC, const ushort* __restrict__ Wt,
        const float* __restrict__ bias, ushort* __restrict__ out, int N) {
    constexpr int KS = KPAD / 32;
    constexpr int NWN = 2;
    constexpr int FW = F / NWN;
    constexpr int NT = FW / 16;
    __shared__ ushort At[64 * LDA];
    const int node0 = blockIdx.x * 64;
    const int tid = threadIdx.x;
    const int lane = tid & 63;
    const int wv = tid >> 6;
    const int wm = wv & 3;
    const int wn = wv >> 2;

    {
        constexpr int NV = WA / 8;
        for (int idx = tid; idx < 64 * NV; idx += 512) {
            int m = idx / NV, q = idx - m * NV;
            int i = node0 + m;
            uint4 v = make_uint4(0, 0, 0, 0);
            if (i < N) v = *reinterpret_cast<const uint4*>(&inA[(size_t)i * WA + q * 8]);
            *reinterpret_cast<uint4*>(&At[m * LDA + q * 8]) = v;
        }
    }
    if constexpr (WB > 0) {
        constexpr int NV = WB / 8;
        for (int idx = tid; idx < 64 * NV; idx += 512) {
            int m = idx / NV, q = idx - m * NV;
            int i = node0 + m;
            uint4 v = make_uint4(0, 0, 0, 0);
            if (i < N) v = *reinterpret_cast<const uint4*>(&inB[(size_t)i * WB + q * 8]);
            *reinterpret_cast<uint4*>(&At[m * LDA + WA + q * 8]) = v;
        }
    }
    if constexpr (WC > 0) {
        constexpr int NV = WC / 8;
        for (int idx = tid; idx < 64 * NV; idx += 512) {
            int m = idx / NV, q = idx - m * NV;
            int i = node0 + m;
            uint4 v = make_uint4(0, 0, 0, 0);
            if (i < N) v = *reinterpret_cast<const uint4*>(&inC[(size_t)i * WC + q * 8]);
            *reinterpret_cast<uint4*>(&At[m * LDA + WA + WB + q * 8]) = v;
        }
    }
    {
        constexpr int PAD = LDA - K;
        for (int idx = tid; idx < 64 * PAD; idx += 512) {
            int m = idx / PAD, k = K + (idx - m * PAD);
            At[m * LDA + k] = 0;
        }
    }
    __syncthreads();

    f32x4 acc[NT];
    #pragma unroll
    for (int nt = 0; nt < NT; nt++) acc[nt] = (f32x4){0.f, 0.f, 0.f, 0.f};

    const int r15 = lane & 15, kg = lane >> 4;
    const ushort* arow = &At[(wm * 16 + r15) * LDA + kg * 8];
    const ushort* wbase = &Wt[(size_t)(wn * FW + r15) * KPAD + kg * 8];
    #pragma unroll
    for (int kc = 0; kc < KS; kc++) {
        short8 a = *reinterpret_cast<const short8*>(arow + kc * 32);
        #pragma unroll
        for (int nt = 0; nt < NT; nt++) {
            short8 b = *reinterpret_cast<const short8*>(
                wbase + (size_t)nt * 16 * KPAD + kc * 32);
            acc[nt] = __builtin_amdgcn_mfma_f32_16x16x32_bf16(a, b, acc[nt], 0, 0, 0);
        }
    }

    #pragma unroll
    for (int nt = 0; nt < NT; nt++) {
        int colg = wn * FW + nt * 16 + r15;
        float bv = bias[colg];
        #pragma unroll
        for (int reg = 0; reg < 4; reg++) {
            int row = node0 + wm * 16 + kg * 4 + reg;
            if (row < N) {
                float v = fmaxf(acc[nt][reg] + bv, 0.f);
                out[(size_t)row * F + colg] = f2bf(v);
            }
        }
    }
}

// ---------------- pool: pooled[g][c] = max over rows of graph g ----------------

#define PSPLIT 8
__global__ __launch_bounds__(256) void pool_k(const ushort* __restrict__ h3,
                                              const int* __restrict__ gstart,
                                              float* __restrict__ pooled) {
    int g = blockIdx.x, sp = blockIdx.y, c = threadIdx.x;
    int i0 = gstart[g], i1 = gstart[g + 1];
    int len = i1 - i0;
    int per = (len + PSPLIT - 1) / PSPLIT;
    int s = i0 + sp * per;
    int e = min(s + per, i1);
    if (s >= e) return;
    float m0 = 0.f, m1 = 0.f, m2 = 0.f, m3 = 0.f; // relu outputs are >= 0
    int i = s;
    for (; i + 3 < e; i += 4) {
        m0 = fmaxf(m0, __uint_as_float((uint)h3[(size_t)i * 256 + c] << 16));
        m1 = fmaxf(m1, __uint_as_float((uint)h3[(size_t)(i + 1) * 256 + c] << 16));
        m2 = fmaxf(m2, __uint_as_float((uint)h3[(size_t)(i + 2) * 256 + c] << 16));
        m3 = fmaxf(m3, __uint_as_float((uint)h3[(size_t)(i + 3) * 256 + c] << 16));
    }
    for (; i < e; i++)
        m0 = fmaxf(m0, __uint_as_float((uint)h3[(size_t)i * 256 + c] << 16));
    float mm = fmaxf(fmaxf(m0, m1), fmaxf(m2, m3));
    atomicMax(reinterpret_cast<int*>(&pooled[g * 256 + c]), __float_as_int(mm));
}

// ---------------- head: logits -> log_softmax, softmax ----------------

__global__ __launch_bounds__(320) void head_k(const float* __restrict__ pooled,
                                              const float* __restrict__ Wl,
                                              const float* __restrict__ bl,
                                              float* __restrict__ out) {
    __shared__ float lg[GG][10];
    __shared__ float lse[GG];
    int t = threadIdx.x;
    int g = t / 10, c = t % 10;
    float acc = bl[c];
    for (int k = 0; k < 256; k++) acc = fmaf(pooled[g * 256 + k], Wl[k * 10 + c], acc);
    lg[g][c] = acc;
    __syncthreads();
    if (c == 0) {
        float mx = -1e30f;
        for (int j = 0; j < 10; j++) mx = fmaxf(mx, lg[g][j]);
        float s = 0.f;
        for (int j = 0; j < 10; j++) s += expf(lg[g][j] - mx);
        lse[g] = mx + logf(s);
    }
    __syncthreads();
    float o = acc - lse[g];
    out[g * 10 + c] = o;             // log_softmax
    out[320 + g * 10 + c] = expf(o); // softmax(log_softmax(x)) == exp(log_softmax(x))
}

// ---------------- launch ----------------

extern "C" void kernel_launch(void* const* d_in, const int* in_sizes, int n_in,
                              void* d_out, int out_size, void* d_ws, size_t ws_size,
                              hipStream_t stream) {
    const int N = NN, E = EE;
    const float* nrm = (const float*)d_in[0];
    const float* pos = (const float*)d_in[1];
    const float* x   = (const float*)d_in[2];
    const int* ei    = (const int*)d_in[3];
    const int* batch = (const int*)d_in[4];
    const float* W1 = (const float*)d_in[5];
    const float* b1 = (const float*)d_in[6];
    const float* W2 = (const float*)d_in[7];
    const float* b2 = (const float*)d_in[8];
    const float* W3 = (const float*)d_in[9];
    const float* b3 = (const float*)d_in[10];
    const float* Wl = (const float*)d_in[11];
    const float* bl = (const float*)d_in[12];

    const int* esrc = ei;
    const int* edst = ei + E;

    char* w = (char*)d_ws;
    auto carve = [&](size_t bytes) {
        void* p = (void*)w;
        w += (bytes + 255) & ~(size_t)255;
        return p;
    };
    int* cnt      = (int*)carve((size_t)N * 4);
    int* wp       = (int*)carve((size_t)N * 4);
    int* rowptr   = (int*)carve((size_t)(N + 1) * 4);
    int* bsum     = (int*)carve((size_t)NB * 4);
    ushort* col   = (ushort*)carve((size_t)E * 2);
    int* gstart   = (int*)carve((size_t)(GG + 1) * 4);
    ushort* inpb  = (ushort*)carve((size_t)N * 8 * 2);
    ushort* agg1  = (ushort*)carve((size_t)N * 8 * 2);
    ushort* h1    = (ushort*)carve((size_t)N * 64 * 2);
    ushort* aggh1 = (ushort*)carve((size_t)N * 64 * 2);
    ushort* h2    = (ushort*)carve((size_t)N * 128 * 2);
    ushort* aggh2 = (ushort*)carve((size_t)N * 128 * 2);
    ushort* h3    = (ushort*)carve((size_t)N * 256 * 2);
    ushort* Wt1   = (ushort*)carve((size_t)64 * 32 * 2);
    ushort* Wt2   = (ushort*)carve((size_t)128 * 96 * 2);
    ushort* Wt3   = (ushort*)carve((size_t)256 * 224 * 2);
    float* pooled = (float*)carve((size_t)GG * 256 * 4);

    hipMemsetAsync(cnt, 0, (size_t)N * 4, stream);
    hipMemsetAsync(pooled, 0, (size_t)GG * 256 * 4, stream);

    // CSR build
    hist_k<<<(E + 255) / 256, 256, 0, stream>>>(edst, cnt, E);
    scan1_k<<<NB, SCB, 0, stream>>>(cnt, bsum, N);
    scan2_k<<<1, 64, 0, stream>>>(bsum, rowptr, NB, E);
    scan3_k<<<NB, SCB, 0, stream>>>(cnt, bsum, rowptr, wp, N);
    scatter_k<<<(E + 255) / 256, 256, 0, stream>>>(esrc, edst, wp, col, E);

    // setup
    prep_k<<<(N + 255) / 256, 256, 0, stream>>>(nrm, pos, x, batch, inpb, gstart, N);
    {
        const int TOT = 64 * 32 + 128 * 96 + 256 * 224;
        wtp_all_k<<<(TOT + 255) / 256, 256, 0, stream>>>(W1, Wt1, W2, Wt2, W3, Wt3);
    }

    // layer 1
    aggb_k<8><<<(N + 255) / 256, 256, 0, stream>>>(rowptr, col, inpb, agg1, N);
    mfma_transform_k<8, 32, 40, 64, 8, 0, 0><<<(N + 63) / 64, 512, 0, stream>>>(
        agg1, nullptr, nullptr, Wt1, b1, h1, N);

    // layer 2
    aggb_k<64><<<(N + 31) / 32, 256, 0, stream>>>(rowptr, col, h1, aggh1, N);
    mfma_transform_k<72, 96, 104, 128, 64, 8, 0><<<(N + 63) / 64, 512, 0, stream>>>(
        aggh1, agg1, nullptr, Wt2, b2, h2, N);

    // layer 3
    aggb_k<128><<<(N + 15) / 16, 256, 0, stream>>>(rowptr, col, h2, aggh2, N);
    mfma_transform_k<200, 224, 232, 256, 64, 8, 128><<<(N + 63) / 64, 512, 0, stream>>>(
        aggh1, agg1, aggh2, Wt3, b3, h3, N);

    // pool + head
    pool_k<<<dim3(GG, PSPLIT), 256, 0, stream>>>(h3, gstart, pooled);
    head_k<<<1, 320, 0, stream>>>(pooled, Wl, bl, (float*)d_out);
}

// Round 7
// 244.226 us; speedup vs baseline: 2.5919x; 1.0308x over previous
//
#include <hip/hip_runtime.h>
#include <hip/hip_bf16.h>

#define NN 50000
#define EE 800000
#define GG 32
#define SCB 512                      // scan elements per block
#define NB ((NN + SCB - 1) / SCB)    // 98 scan blocks

using short8 = __attribute__((ext_vector_type(8))) short;
using f32x4  = __attribute__((ext_vector_type(4))) float;

__device__ __forceinline__ ushort f2bf(float f) {
    __hip_bfloat16 hb = __float2bfloat16(f);
    return *reinterpret_cast<ushort*>(&hb);
}

// ---------------- CSR build ----------------

__global__ void hist_k(const int* __restrict__ dst, int* __restrict__ cnt, int E) {
    int e = blockIdx.x * blockDim.x + threadIdx.x;
    if (e < E) atomicAdd(&cnt[dst[e]], 1);
}

// phase 1: per-block sums of cnt
__global__ __launch_bounds__(SCB) void scan1_k(const int* __restrict__ cnt,
                                               int* __restrict__ bsum, int N) {
    __shared__ int ws[SCB / 64];
    int tid = threadIdx.x, lane = tid & 63, w = tid >> 6;
    int i = blockIdx.x * SCB + tid;
    int s = (i < N) ? cnt[i] : 0;
    #pragma unroll
    for (int off = 32; off >= 1; off >>= 1) s += __shfl_down(s, off, 64);
    if (lane == 0) ws[w] = s;
    __syncthreads();
    if (tid == 0) {
        int t = 0;
        #pragma unroll
        for (int j = 0; j < SCB / 64; j++) t += ws[j];
        bsum[blockIdx.x] = t;
    }
}

// phase 2: exclusive scan of the NB block sums (single wave), rowptr[N]=E
__global__ __launch_bounds__(64) void scan2_k(int* __restrict__ bsum,
                                              int* __restrict__ rowptr, int nb, int E) {
    int lane = threadIdx.x;
    int carry = 0;
    for (int base = 0; base < nb; base += 64) {
        int v = (base + lane < nb) ? bsum[base + lane] : 0;
        int s = v;
        #pragma unroll
        for (int off = 1; off < 64; off <<= 1) {
            int t = __shfl_up(s, off, 64);
            if (lane >= off) s += t;
        }
        if (base + lane < nb) bsum[base + lane] = carry + s - v;
        carry += __shfl(s, 63, 64);
    }
    if (lane == 0) rowptr[NN] = E;
}

// phase 3: per-block exclusive scan + block offset -> rowptr & wp
__global__ __launch_bounds__(SCB) void scan3_k(const int* __restrict__ cnt,
                                               const int* __restrict__ bsum,
                                               int* __restrict__ rowptr,
                                               int* __restrict__ wp, int N) {
    __shared__ int ws[SCB / 64];
    int tid = threadIdx.x, lane = tid & 63, w = tid >> 6;
    int i = blockIdx.x * SCB + tid;
    int v = (i < N) ? cnt[i] : 0;
    int s = v;
    #pragma unroll
    for (int off = 1; off < 64; off <<= 1) {
        int t = __shfl_up(s, off, 64);
        if (lane >= off) s += t;
    }
    if (lane == 63) ws[w] = s;
    __syncthreads();
    if (w == 0 && lane < SCB / 64) {
        int t = ws[lane];
        #pragma unroll
        for (int off = 1; off < SCB / 64; off <<= 1) {
            int u = __shfl_up(t, off, 64);
            if (lane >= off) t += u;
        }
        ws[lane] = t;
    }
    __syncthreads();
    int excl = (w ? ws[w - 1] : 0) + s - v + bsum[blockIdx.x];
    if (i < N) { rowptr[i] = excl; wp[i] = excl; }
}

__global__ void scatter_k(const int* __restrict__ src, const int* __restrict__ dst,
                          int* __restrict__ wp, ushort* __restrict__ col, int E) {
    int e = blockIdx.x * blockDim.x + threadIdx.x;
    if (e < E) {
        int p = atomicAdd(&wp[dst[e]], 1);
        __builtin_nontemporal_store((ushort)src[e], &col[p]);
    }
}

// ---------------- setup: inp (bf16) + graph starts ----------------

__global__ void prep_k(const float* __restrict__ nrm, const float* __restrict__ pos,
                       const float* __restrict__ x, const int* __restrict__ batch,
                       ushort* __restrict__ inp, int* __restrict__ gstart, int N) {
    int i = blockIdx.x * blockDim.x + threadIdx.x;
    if (i >= N) return;
    float v[8];
    v[0] = nrm[i * 3]; v[1] = nrm[i * 3 + 1]; v[2] = nrm[i * 3 + 2];
    v[3] = pos[i * 3]; v[4] = pos[i * 3 + 1]; v[5] = pos[i * 3 + 2];
    v[6] = x[i * 2];   v[7] = x[i * 2 + 1];
    uint4 d;
    d.x = (uint)f2bf(v[0]) | ((uint)f2bf(v[1]) << 16);
    d.y = (uint)f2bf(v[2]) | ((uint)f2bf(v[3]) << 16);
    d.z = (uint)f2bf(v[4]) | ((uint)f2bf(v[5]) << 16);
    d.w = (uint)f2bf(v[6]) | ((uint)f2bf(v[7]) << 16);
    *reinterpret_cast<uint4*>(&inp[(size_t)i * 8]) = d;

    int b = batch[i];
    if (i == 0) { for (int g = 0; g <= b; g++) gstart[g] = 0; }
    else {
        int p = batch[i - 1];
        for (int g = p + 1; g <= b; g++) gstart[g] = i;
    }
    if (i == N - 1) { for (int g = b + 1; g <= GG; g++) gstart[g] = N; }
}

// ---------------- transposed bf16 weights (all three in one kernel) ----------------
// Wt[n][k] = W[k][n] (+ fold of W3 rows 200:208 into 64:72), zero-padded to KPAD.

__device__ __forceinline__ void wtp_one(const float* W, ushort* Wt, int K, int F,
                                        int KPAD, int fold, int idx) {
    int n = idx / KPAD, k = idx - n * KPAD;
    float v = 0.f;
    if (k < K) {
        v = W[(size_t)k * F + n];
        if (fold && k >= 64 && k < 72) v += W[(size_t)(k + 136) * F + n];
    }
    Wt[idx] = f2bf(v);
}

__global__ void wtp_all_k(const float* __restrict__ W1, ushort* __restrict__ Wt1,
                          const float* __restrict__ W2, ushort* __restrict__ Wt2,
                          const float* __restrict__ W3, ushort* __restrict__ Wt3) {
    const int S1 = 64 * 32, S2 = 128 * 96, S3 = 256 * 224;
    int idx = blockIdx.x * blockDim.x + threadIdx.x;
    if (idx < S1) { wtp_one(W1, Wt1, 8, 64, 32, 0, idx); return; }
    idx -= S1;
    if (idx < S2) { wtp_one(W2, Wt2, 72, 128, 96, 0, idx); return; }
    idx -= S2;
    if (idx < S3) wtp_one(W3, Wt3, 200, 256, 224, 1, idx);
}

// ---------------- aggregation (bf16 in, f32 acc, bf16 out) ----------------

__device__ __forceinline__ void acc8(uint4 v, float* a) {
    a[0] += __uint_as_float(v.x << 16); a[1] += __uint_as_float(v.x & 0xffff0000u);
    a[2] += __uint_as_float(v.y << 16); a[3] += __uint_as_float(v.y & 0xffff0000u);
    a[4] += __uint_as_float(v.z << 16); a[5] += __uint_as_float(v.z & 0xffff0000u);
    a[6] += __uint_as_float(v.w << 16); a[7] += __uint_as_float(v.w & 0xffff0000u);
}

template <int F>
__global__ __launch_bounds__(256, 6) void aggb_k(const int* __restrict__ rowptr,
                                                 const ushort* __restrict__ col,
                                                 const ushort* __restrict__ src,
                                                 ushort* __restrict__ dst, int N) {
    constexpr int TPN = F / 8;
    constexpr int Q = 256 / TPN;
    int i = blockIdx.x * Q + threadIdx.x / TPN;
    int f8 = (threadIdx.x % TPN) * 8;
    if (i >= N) return;
    int e0 = rowptr[i], e1 = rowptr[i + 1];
    float a0[8] = {0,0,0,0,0,0,0,0};
    float a1[8] = {0,0,0,0,0,0,0,0};
    float a2[8] = {0,0,0,0,0,0,0,0};
    float a3[8] = {0,0,0,0,0,0,0,0};
    int e = e0;
    for (; e + 3 < e1; e += 4) {
        int s0 = col[e], s1 = col[e + 1], s2 = col[e + 2], s3 = col[e + 3];
        uint4 v0 = *reinterpret_cast<const uint4*>(&src[(size_t)s0 * F + f8]);
        uint4 v1 = *reinterpret_cast<const uint4*>(&src[(size_t)s1 * F + f8]);
        uint4 v2 = *reinterpret_cast<const uint4*>(&src[(size_t)s2 * F + f8]);
        uint4 v3 = *reinterpret_cast<const uint4*>(&src[(size_t)s3 * F + f8]);
        acc8(v0, a0); acc8(v1, a1); acc8(v2, a2); acc8(v3, a3);
    }
    for (; e < e1; e++) {
        uint4 v0 = *reinterpret_cast<const uint4*>(&src[(size_t)col[e] * F + f8]);
        acc8(v0, a0);
    }
    uint4 o;
    o.x = (uint)f2bf(a0[0]+a1[0]+a2[0]+a3[0]) | ((uint)f2bf(a0[1]+a1[1]+a2[1]+a3[1]) << 16);
    o.y = (uint)f2bf(a0[2]+a1[2]+a2[2]+a3[2]) | ((uint)f2bf(a0[3]+a1[3]+a2[3]+a3[3]) << 16);
    o.z = (uint)f2bf(a0[4]+a1[4]+a2[4]+a3[4]) | ((uint)f2bf(a0[5]+a1[5]+a2[5]+a3[5]) << 16);
    o.w = (uint)f2bf(a0[6]+a1[6]+a2[6]+a3[6]) | ((uint)f2bf(a0[7]+a1[7]+a2[7]+a3[7]) << 16);
    *reinterpret_cast<uint4*>(&dst[(size_t)i * F + f8]) = o;
}

// ---------------- MFMA dense transform ----------------
// out[N][F] = relu(concat(inA,inB,inC)[N][K] @ W[K][F] + b), all features bf16.
// 512 threads = 8 waves in a 2(M) x 4(N) grid over BM=64 rows. Each wave:
// 32 rows (2 strips of 16) x F/4 cols. A-fragments held in registers (read
// once from LDS); per 16-col tile all KS B-loads issued as ONE independent
// batch (explicit b[KS] array) feeding 2*KS MFMAs -> ~200cy exposed latency
// per batch instead of a serial load->MFMA chain (R6 lesson: VGPR=48 meant
// the compiler never hoisted B loads on its own).
// Fragment layouts (m89/m91-verified): A/B lane l -> row l&15, k=(l>>4)*8+e;
// C/D: col=lane&15, row=(lane>>4)*4+reg.

template <int K, int KPAD, int LDA, int F, int WA, int WB, int WC>
__global__ __launch_bounds__(512) void mfma_transform_k(
        const ushort* __restrict__ inA, const ushort* __restrict__ inB,
        const ushort* __restrict__ inC, const ushort* __restrict__ Wt,
        const float* __restrict__ bias, ushort* __restrict__ out, int N) {
    constexpr int KS = KPAD / 32;
    constexpr int FW = F / 4;              // cols per wave
    constexpr int NT = FW / 16;            // 16-col tiles per wave
    __shared__ ushort At[64 * LDA];
    const int node0 = blockIdx.x * 64;
    const int tid = threadIdx.x;
    const int lane = tid & 63;
    const int wv = tid >> 6;
    const int wm = wv & 1;                 // M-group (32 rows)
    const int wn = wv >> 1;                // N-quarter

    // ---- stage A rows into LDS as [64][LDA] (uint4 = 8 bf16 per move) ----
    {
        constexpr int NV = WA / 8;
        for (int idx = tid; idx < 64 * NV; idx += 512) {
            int m = idx / NV, q = idx - m * NV;
            int i = node0 + m;
            uint4 v = make_uint4(0, 0, 0, 0);
            if (i < N) v = *reinterpret_cast<const uint4*>(&inA[(size_t)i * WA + q * 8]);
            *reinterpret_cast<uint4*>(&At[m * LDA + q * 8]) = v;
        }
    }
    if constexpr (WB > 0) {
        constexpr int NV = WB / 8;
        for (int idx = tid; idx < 64 * NV; idx += 512) {
            int m = idx / NV, q = idx - m * NV;
            int i = node0 + m;
            uint4 v = make_uint4(0, 0, 0, 0);
            if (i < N) v = *reinterpret_cast<const uint4*>(&inB[(size_t)i * WB + q * 8]);
            *reinterpret_cast<uint4*>(&At[m * LDA + WA + q * 8]) = v;
        }
    }
    if constexpr (WC > 0) {
        constexpr int NV = WC / 8;
        for (int idx = tid; idx < 64 * NV; idx += 512) {
            int m = idx / NV, q = idx - m * NV;
            int i = node0 + m;
            uint4 v = make_uint4(0, 0, 0, 0);
            if (i < N) v = *reinterpret_cast<const uint4*>(&inC[(size_t)i * WC + q * 8]);
            *reinterpret_cast<uint4*>(&At[m * LDA + WA + WB + q * 8]) = v;
        }
    }
    {   // zero-pad k in [K, LDA)
        constexpr int PAD = LDA - K;
        for (int idx = tid; idx < 64 * PAD; idx += 512) {
            int m = idx / PAD, k = K + (idx - m * PAD);
            At[m * LDA + k] = 0;
        }
    }
    __syncthreads();

    const int r15 = lane & 15, kg = lane >> 4;

    // A-fragments: 2 strips x KS, resident in registers
    short8 a[2][KS];
    #pragma unroll
    for (int s = 0; s < 2; s++)
        #pragma unroll
        for (int kc = 0; kc < KS; kc++)
            a[s][kc] = *reinterpret_cast<const short8*>(
                &At[(wm * 32 + s * 16 + r15) * LDA + kg * 8 + kc * 32]);

    f32x4 acc[2][NT];
    #pragma unroll
    for (int s = 0; s < 2; s++)
        #pragma unroll
        for (int nt = 0; nt < NT; nt++) acc[s][nt] = (f32x4){0.f, 0.f, 0.f, 0.f};

    const ushort* wbase = &Wt[(size_t)(wn * FW + r15) * KPAD + kg * 8];
    #pragma unroll
    for (int nt = 0; nt < NT; nt++) {
        short8 b[KS];
        #pragma unroll
        for (int kc = 0; kc < KS; kc++)
            b[kc] = *reinterpret_cast<const short8*>(
                wbase + (size_t)nt * 16 * KPAD + kc * 32);
        #pragma unroll
        for (int kc = 0; kc < KS; kc++) {
            acc[0][nt] = __builtin_amdgcn_mfma_f32_16x16x32_bf16(a[0][kc], b[kc], acc[0][nt], 0, 0, 0);
            acc[1][nt] = __builtin_amdgcn_mfma_f32_16x16x32_bf16(a[1][kc], b[kc], acc[1][nt], 0, 0, 0);
        }
    }

    #pragma unroll
    for (int s = 0; s < 2; s++)
        #pragma unroll
        for (int nt = 0; nt < NT; nt++) {
            int colg = wn * FW + nt * 16 + r15;
            float bv = bias[colg];
            #pragma unroll
            for (int reg = 0; reg < 4; reg++) {
                int row = node0 + wm * 32 + s * 16 + kg * 4 + reg;
                if (row < N) {
                    float v = fmaxf(acc[s][nt][reg] + bv, 0.f);
                    out[(size_t)row * F + colg] = f2bf(v);
                }
            }
        }
}

// ---------------- pool: pooled[g][c] = max over rows of graph g ----------------

#define PSPLIT 8
__global__ __launch_bounds__(256) void pool_k(const ushort* __restrict__ h3,
                                              const int* __restrict__ gstart,
                                              float* __restrict__ pooled) {
    int g = blockIdx.x, sp = blockIdx.y, c = threadIdx.x;
    int i0 = gstart[g], i1 = gstart[g + 1];
    int len = i1 - i0;
    int per = (len + PSPLIT - 1) / PSPLIT;
    int s = i0 + sp * per;
    int e = min(s + per, i1);
    if (s >= e) return;
    float m0 = 0.f, m1 = 0.f, m2 = 0.f, m3 = 0.f; // relu outputs are >= 0
    int i = s;
    for (; i + 3 < e; i += 4) {
        m0 = fmaxf(m0, __uint_as_float((uint)h3[(size_t)i * 256 + c] << 16));
        m1 = fmaxf(m1, __uint_as_float((uint)h3[(size_t)(i + 1) * 256 + c] << 16));
        m2 = fmaxf(m2, __uint_as_float((uint)h3[(size_t)(i + 2) * 256 + c] << 16));
        m3 = fmaxf(m3, __uint_as_float((uint)h3[(size_t)(i + 3) * 256 + c] << 16));
    }
    for (; i < e; i++)
        m0 = fmaxf(m0, __uint_as_float((uint)h3[(size_t)i * 256 + c] << 16));
    float mm = fmaxf(fmaxf(m0, m1), fmaxf(m2, m3));
    atomicMax(reinterpret_cast<int*>(&pooled[g * 256 + c]), __float_as_int(mm));
}

// ---------------- head: logits -> log_softmax, softmax ----------------

__global__ __launch_bounds__(320) void head_k(const float* __restrict__ pooled,
                                              const float* __restrict__ Wl,
                                              const float* __restrict__ bl,
                                              float* __restrict__ out) {
    __shared__ float lg[GG][10];
    __shared__ float lse[GG];
    int t = threadIdx.x;
    int g = t / 10, c = t % 10;
    float acc = bl[c];
    for (int k = 0; k < 256; k++) acc = fmaf(pooled[g * 256 + k], Wl[k * 10 + c], acc);
    lg[g][c] = acc;
    __syncthreads();
    if (c == 0) {
        float mx = -1e30f;
        for (int j = 0; j < 10; j++) mx = fmaxf(mx, lg[g][j]);
        float s = 0.f;
        for (int j = 0; j < 10; j++) s += expf(lg[g][j] - mx);
        lse[g] = mx + logf(s);
    }
    __syncthreads();
    float o = acc - lse[g];
    out[g * 10 + c] = o;             // log_softmax
    out[320 + g * 10 + c] = expf(o); // softmax(log_softmax(x)) == exp(log_softmax(x))
}

// ---------------- launch ----------------

extern "C" void kernel_launch(void* const* d_in, const int* in_sizes, int n_in,
                              void* d_out, int out_size, void* d_ws, size_t ws_size,
                              hipStream_t stream) {
    const int N = NN, E = EE;
    const float* nrm = (const float*)d_in[0];
    const float* pos = (const float*)d_in[1];
    const float* x   = (const float*)d_in[2];
    const int* ei    = (const int*)d_in[3];
    const int* batch = (const int*)d_in[4];
    const float* W1 = (const float*)d_in[5];
    const float* b1 = (const float*)d_in[6];
    const float* W2 = (const float*)d_in[7];
    const float* b2 = (const float*)d_in[8];
    const float* W3 = (const float*)d_in[9];
    const float* b3 = (const float*)d_in[10];
    const float* Wl = (const float*)d_in[11];
    const float* bl = (const float*)d_in[12];

    const int* esrc = ei;
    const int* edst = ei + E;

    char* w = (char*)d_ws;
    auto carve = [&](size_t bytes) {
        void* p = (void*)w;
        w += (bytes + 255) & ~(size_t)255;
        return p;
    };
    int* cnt      = (int*)carve((size_t)N * 4);
    int* wp       = (int*)carve((size_t)N * 4);
    int* rowptr   = (int*)carve((size_t)(N + 1) * 4);
    int* bsum     = (int*)carve((size_t)NB * 4);
    ushort* col   = (ushort*)carve((size_t)E * 2);
    int* gstart   = (int*)carve((size_t)(GG + 1) * 4);
    ushort* inpb  = (ushort*)carve((size_t)N * 8 * 2);
    ushort* agg1  = (ushort*)carve((size_t)N * 8 * 2);
    ushort* h1    = (ushort*)carve((size_t)N * 64 * 2);
    ushort* aggh1 = (ushort*)carve((size_t)N * 64 * 2);
    ushort* h2    = (ushort*)carve((size_t)N * 128 * 2);
    ushort* aggh2 = (ushort*)carve((size_t)N * 128 * 2);
    ushort* h3    = (ushort*)carve((size_t)N * 256 * 2);
    ushort* Wt1   = (ushort*)carve((size_t)64 * 32 * 2);
    ushort* Wt2   = (ushort*)carve((size_t)128 * 96 * 2);
    ushort* Wt3   = (ushort*)carve((size_t)256 * 224 * 2);
    float* pooled = (float*)carve((size_t)GG * 256 * 4);

    hipMemsetAsync(cnt, 0, (size_t)N * 4, stream);
    hipMemsetAsync(pooled, 0, (size_t)GG * 256 * 4, stream);

    // CSR build
    hist_k<<<(E + 255) / 256, 256, 0, stream>>>(edst, cnt, E);
    scan1_k<<<NB, SCB, 0, stream>>>(cnt, bsum, N);
    scan2_k<<<1, 64, 0, stream>>>(bsum, rowptr, NB, E);
    scan3_k<<<NB, SCB, 0, stream>>>(cnt, bsum, rowptr, wp, N);
    scatter_k<<<(E + 255) / 256, 256, 0, stream>>>(esrc, edst, wp, col, E);

    // setup
    prep_k<<<(N + 255) / 256, 256, 0, stream>>>(nrm, pos, x, batch, inpb, gstart, N);
    {
        const int TOT = 64 * 32 + 128 * 96 + 256 * 224;
        wtp_all_k<<<(TOT + 255) / 256, 256, 0, stream>>>(W1, Wt1, W2, Wt2, W3, Wt3);
    }

    // layer 1
    aggb_k<8><<<(N + 255) / 256, 256, 0, stream>>>(rowptr, col, inpb, agg1, N);
    mfma_transform_k<8, 32, 40, 64, 8, 0, 0><<<(N + 63) / 64, 512, 0, stream>>>(
        agg1, nullptr, nullptr, Wt1, b1, h1, N);

    // layer 2
    aggb_k<64><<<(N + 31) / 32, 256, 0, stream>>>(rowptr, col, h1, aggh1, N);
    mfma_transform_k<72, 96, 104, 128, 64, 8, 0><<<(N + 63) / 64, 512, 0, stream>>>(
        aggh1, agg1, nullptr, Wt2, b2, h2, N);

    // layer 3
    aggb_k<128><<<(N + 15) / 16, 256, 0, stream>>>(rowptr, col, h2, aggh2, N);
    mfma_transform_k<200, 224, 232, 256, 64, 8, 128><<<(N + 63) / 64, 512, 0, stream>>>(
        aggh1, agg1, aggh2, Wt3, b3, h3, N);

    // pool + head
    pool_k<<<dim3(GG, PSPLIT), 256, 0, stream>>>(h3, gstart, pooled);
    head_k<<<1, 320, 0, stream>>>(pooled, Wl, bl, (float*)d_out);
}

// Round 8
// 185.823 us; speedup vs baseline: 3.4064x; 1.3143x over previous
//
#include <hip/hip_runtime.h>
#include <hip/hip_bf16.h>

#define NN 50000
#define EE 800000
#define GG 32
#define SCB 512                       // scan elements per block

// bucket sort geometry
#define BSH 6                         // bucket = dst >> 6 (64 nodes/bucket)
#define NBUK 782                      // ceil(50000/64)
#define NBLK1 128                     // edge blocks in pass 1
#define EPB (EE / NBLK1)              // 6250 edges per block
#define MH (NBUK * NBLK1)             // 100096 counters to scan
#define NB2 ((MH + SCB - 1) / SCB)    // 196 scan blocks
#define CAP2 2048                     // max edges per bucket (mean 1023, sigma 32)

using short8 = __attribute__((ext_vector_type(8))) short;
using f32x4  = __attribute__((ext_vector_type(4))) float;

__device__ __forceinline__ ushort f2bf(float f) {
    __hip_bfloat16 hb = __float2bfloat16(f);
    return *reinterpret_cast<ushort*>(&hb);
}

// ---------------- CSR build: two-level LDS bucket sort ----------------

// pass 1a: per-(bucket,block) histogram via LDS atomics
__global__ __launch_bounds__(256) void bhist_k(const int* __restrict__ edst,
                                               int* __restrict__ hist) {
    __shared__ uint cnt[NBUK];
    int tid = threadIdx.x, blk = blockIdx.x;
    for (int i = tid; i < NBUK; i += 256) cnt[i] = 0;
    __syncthreads();
    int base = blk * EPB;
    for (int i = tid; i < EPB; i += 256)
        atomicAdd(&cnt[(uint)edst[base + i] >> BSH], 1u);
    __syncthreads();
    for (int b = tid; b < NBUK; b += 256)
        hist[(size_t)b * NBLK1 + blk] = (int)cnt[b];   // bucket-major layout
}

// generic 3-phase exclusive scan over M elements
__global__ __launch_bounds__(SCB) void scan1_k(const int* __restrict__ in,
                                               int* __restrict__ bsum, int M) {
    __shared__ int ws[SCB / 64];
    int tid = threadIdx.x, lane = tid & 63, w = tid >> 6;
    int i = blockIdx.x * SCB + tid;
    int s = (i < M) ? in[i] : 0;
    #pragma unroll
    for (int off = 32; off >= 1; off >>= 1) s += __shfl_down(s, off, 64);
    if (lane == 0) ws[w] = s;
    __syncthreads();
    if (tid == 0) {
        int t = 0;
        #pragma unroll
        for (int j = 0; j < SCB / 64; j++) t += ws[j];
        bsum[blockIdx.x] = t;
    }
}

__global__ __launch_bounds__(64) void scan2g_k(int* __restrict__ bsum, int nb) {
    int lane = threadIdx.x;
    int carry = 0;
    for (int base = 0; base < nb; base += 64) {
        int v = (base + lane < nb) ? bsum[base + lane] : 0;
        int s = v;
        #pragma unroll
        for (int off = 1; off < 64; off <<= 1) {
            int t = __shfl_up(s, off, 64);
            if (lane >= off) s += t;
        }
        if (base + lane < nb) bsum[base + lane] = carry + s - v;
        carry += __shfl(s, 63, 64);
    }
}

__global__ __launch_bounds__(SCB) void scan3g_k(const int* __restrict__ in,
                                                const int* __restrict__ bsum,
                                                int* __restrict__ out, int M) {
    __shared__ int ws[SCB / 64];
    int tid = threadIdx.x, lane = tid & 63, w = tid >> 6;
    int i = blockIdx.x * SCB + tid;
    int v = (i < M) ? in[i] : 0;
    int s = v;
    #pragma unroll
    for (int off = 1; off < 64; off <<= 1) {
        int t = __shfl_up(s, off, 64);
        if (lane >= off) s += t;
    }
    if (lane == 63) ws[w] = s;
    __syncthreads();
    if (w == 0 && lane < SCB / 64) {
        int t = ws[lane];
        #pragma unroll
        for (int off = 1; off < SCB / 64; off <<= 1) {
            int u = __shfl_up(t, off, 64);
            if (lane >= off) t += u;
        }
        ws[lane] = t;
    }
    __syncthreads();
    if (i < M) out[i] = (w ? ws[w - 1] : 0) + s - v + bsum[blockIdx.x];
}

// pass 1b: block-local bucket sort in LDS, coalesced run writes of packed
// (bucket<<22 | fine<<16 | src) words at the scanned global offsets.
__global__ __launch_bounds__(256) void bsort1_k(const int* __restrict__ esrc,
                                                const int* __restrict__ edst,
                                                const int* __restrict__ ofs,
                                                uint* __restrict__ packed) {
    __shared__ uint cnt[1024];     // counts -> atomic write cursors
    __shared__ uint lofs0[1024];   // preserved exclusive local offsets
    __shared__ uint goff[NBUK];    // this block's global run starts
    __shared__ uint stage[EPB];    // 25 KB staged packed edges
    __shared__ uint wsum[4];
    int tid = threadIdx.x, blk = blockIdx.x;
    int lane = tid & 63, wv = tid >> 6;

    for (int i = tid; i < 1024; i += 256) cnt[i] = 0;
    __syncthreads();
    int base = blk * EPB;
    for (int i = tid; i < EPB; i += 256)
        atomicAdd(&cnt[(uint)edst[base + i] >> BSH], 1u);
    __syncthreads();

    // block-level exclusive scan of cnt[0..1024)
    uint c0 = cnt[tid * 4 + 0], c1 = cnt[tid * 4 + 1];
    uint c2 = cnt[tid * 4 + 2], c3 = cnt[tid * 4 + 3];
    uint ts = c0 + c1 + c2 + c3;
    uint sc = ts;
    #pragma unroll
    for (int off = 1; off < 64; off <<= 1) {
        uint t = __shfl_up(sc, off, 64);
        if (lane >= off) sc += t;
    }
    if (lane == 63) wsum[wv] = sc;
    __syncthreads();
    uint wbase = 0;
    for (int j = 0; j < wv; j++) wbase += wsum[j];
    uint run = wbase + sc - ts;
    lofs0[tid * 4 + 0] = run;
    lofs0[tid * 4 + 1] = run + c0;
    lofs0[tid * 4 + 2] = run + c0 + c1;
    lofs0[tid * 4 + 3] = run + c0 + c1 + c2;
    cnt[tid * 4 + 0] = run;
    cnt[tid * 4 + 1] = run + c0;
    cnt[tid * 4 + 2] = run + c0 + c1;
    cnt[tid * 4 + 3] = run + c0 + c1 + c2;
    for (int b = tid; b < NBUK; b += 256)
        goff[b] = (uint)ofs[(size_t)b * NBLK1 + blk];
    __syncthreads();

    // scatter into LDS stage (bucket-sorted within block)
    for (int i = tid; i < EPB; i += 256) {
        int d = edst[base + i];
        uint b = (uint)d >> BSH;
        uint pos = atomicAdd(&cnt[b], 1u);
        stage[pos] = (b << 22) | ((uint)(d & 63) << 16) | (uint)esrc[base + i];
    }
    __syncthreads();

    // contiguous run writes to global
    for (int i = tid; i < EPB; i += 256) {
        uint p = stage[i];
        uint b = p >> 22;
        packed[goff[b] + ((uint)i - lofs0[b])] = p & 0x3FFFFFu;
    }
}

// pass 2: one block per bucket -> fine sort, col (coalesced) + rowptr
__global__ __launch_bounds__(256) void bsort2_k(const uint* __restrict__ packed,
                                                const int* __restrict__ ofs,
                                                ushort* __restrict__ col,
                                                int* __restrict__ rowptr) {
    __shared__ uint buf[CAP2];
    __shared__ ushort srt[CAP2];
    __shared__ uint fcnt[64], fofs[64];
    int b = blockIdx.x, tid = threadIdx.x;
    uint g0 = (uint)ofs[(size_t)b * NBLK1];
    uint g1 = (b + 1 < NBUK) ? (uint)ofs[(size_t)(b + 1) * NBLK1] : (uint)EE;
    uint n = g1 - g0;
    if (tid < 64) fcnt[tid] = 0;
    __syncthreads();
    for (uint i = tid; i < n; i += 256) {
        uint p = packed[g0 + i];
        buf[i] = p;
        atomicAdd(&fcnt[(p >> 16) & 63], 1u);
    }
    __syncthreads();
    if (tid < 64) {
        uint v = fcnt[tid], s = v;
        #pragma unroll
        for (int off = 1; off < 64; off <<= 1) {
            uint t = __shfl_up(s, off, 64);
            if (tid >= off) s += t;
        }
        uint e0 = s - v;
        fofs[tid] = e0;
        int node = (b << BSH) + tid;
        if (node < NN) rowptr[node] = (int)(g0 + e0);
    }
    if (b == NBUK - 1 && tid == 0) rowptr[NN] = EE;
    __syncthreads();
    for (uint i = tid; i < n; i += 256) {
        uint p = buf[i];
        uint pos = atomicAdd(&fofs[(p >> 16) & 63], 1u);
        srt[pos] = (ushort)(p & 0xFFFFu);
    }
    __syncthreads();
    for (uint i = tid; i < n; i += 256) col[g0 + i] = srt[i];
}

// ---------------- setup: inp (bf16) + graph starts ----------------

__global__ void prep_k(const float* __restrict__ nrm, const float* __restrict__ pos,
                       const float* __restrict__ x, const int* __restrict__ batch,
                       ushort* __restrict__ inp, int* __restrict__ gstart, int N) {
    int i = blockIdx.x * blockDim.x + threadIdx.x;
    if (i >= N) return;
    float v[8];
    v[0] = nrm[i * 3]; v[1] = nrm[i * 3 + 1]; v[2] = nrm[i * 3 + 2];
    v[3] = pos[i * 3]; v[4] = pos[i * 3 + 1]; v[5] = pos[i * 3 + 2];
    v[6] = x[i * 2];   v[7] = x[i * 2 + 1];
    uint4 d;
    d.x = (uint)f2bf(v[0]) | ((uint)f2bf(v[1]) << 16);
    d.y = (uint)f2bf(v[2]) | ((uint)f2bf(v[3]) << 16);
    d.z = (uint)f2bf(v[4]) | ((uint)f2bf(v[5]) << 16);
    d.w = (uint)f2bf(v[6]) | ((uint)f2bf(v[7]) << 16);
    *reinterpret_cast<uint4*>(&inp[(size_t)i * 8]) = d;

    int b = batch[i];
    if (i == 0) { for (int g = 0; g <= b; g++) gstart[g] = 0; }
    else {
        int p = batch[i - 1];
        for (int g = p + 1; g <= b; g++) gstart[g] = i;
    }
    if (i == N - 1) { for (int g = b + 1; g <= GG; g++) gstart[g] = N; }
}

// ---------------- transposed bf16 weights (all three in one kernel) ----------------

__device__ __forceinline__ void wtp_one(const float* W, ushort* Wt, int K, int F,
                                        int KPAD, int fold, int idx) {
    int n = idx / KPAD, k = idx - n * KPAD;
    float v = 0.f;
    if (k < K) {
        v = W[(size_t)k * F + n];
        if (fold && k >= 64 && k < 72) v += W[(size_t)(k + 136) * F + n];
    }
    Wt[idx] = f2bf(v);
}

__global__ void wtp_all_k(const float* __restrict__ W1, ushort* __restrict__ Wt1,
                          const float* __restrict__ W2, ushort* __restrict__ Wt2,
                          const float* __restrict__ W3, ushort* __restrict__ Wt3) {
    const int S1 = 64 * 32, S2 = 128 * 96, S3 = 256 * 224;
    int idx = blockIdx.x * blockDim.x + threadIdx.x;
    if (idx < S1) { wtp_one(W1, Wt1, 8, 64, 32, 0, idx); return; }
    idx -= S1;
    if (idx < S2) { wtp_one(W2, Wt2, 72, 128, 96, 0, idx); return; }
    idx -= S2;
    if (idx < S3) wtp_one(W3, Wt3, 200, 256, 224, 1, idx);
}

// ---------------- aggregation (bf16 in, f32 acc, bf16 out) ----------------

__device__ __forceinline__ void acc8(uint4 v, float* a) {
    a[0] += __uint_as_float(v.x << 16); a[1] += __uint_as_float(v.x & 0xffff0000u);
    a[2] += __uint_as_float(v.y << 16); a[3] += __uint_as_float(v.y & 0xffff0000u);
    a[4] += __uint_as_float(v.z << 16); a[5] += __uint_as_float(v.z & 0xffff0000u);
    a[6] += __uint_as_float(v.w << 16); a[7] += __uint_as_float(v.w & 0xffff0000u);
}

template <int F>
__global__ __launch_bounds__(256, 6) void aggb_k(const int* __restrict__ rowptr,
                                                 const ushort* __restrict__ col,
                                                 const ushort* __restrict__ src,
                                                 ushort* __restrict__ dst, int N) {
    constexpr int TPN = F / 8;
    constexpr int Q = 256 / TPN;
    int i = blockIdx.x * Q + threadIdx.x / TPN;
    int f8 = (threadIdx.x % TPN) * 8;
    if (i >= N) return;
    int e0 = rowptr[i], e1 = rowptr[i + 1];
    float a0[8] = {0,0,0,0,0,0,0,0};
    float a1[8] = {0,0,0,0,0,0,0,0};
    float a2[8] = {0,0,0,0,0,0,0,0};
    float a3[8] = {0,0,0,0,0,0,0,0};
    int e = e0;
    for (; e + 3 < e1; e += 4) {
        int s0 = col[e], s1 = col[e + 1], s2 = col[e + 2], s3 = col[e + 3];
        uint4 v0 = *reinterpret_cast<const uint4*>(&src[(size_t)s0 * F + f8]);
        uint4 v1 = *reinterpret_cast<const uint4*>(&src[(size_t)s1 * F + f8]);
        uint4 v2 = *reinterpret_cast<const uint4*>(&src[(size_t)s2 * F + f8]);
        uint4 v3 = *reinterpret_cast<const uint4*>(&src[(size_t)s3 * F + f8]);
        acc8(v0, a0); acc8(v1, a1); acc8(v2, a2); acc8(v3, a3);
    }
    for (; e < e1; e++) {
        uint4 v0 = *reinterpret_cast<const uint4*>(&src[(size_t)col[e] * F + f8]);
        acc8(v0, a0);
    }
    uint4 o;
    o.x = (uint)f2bf(a0[0]+a1[0]+a2[0]+a3[0]) | ((uint)f2bf(a0[1]+a1[1]+a2[1]+a3[1]) << 16);
    o.y = (uint)f2bf(a0[2]+a1[2]+a2[2]+a3[2]) | ((uint)f2bf(a0[3]+a1[3]+a2[3]+a3[3]) << 16);
    o.z = (uint)f2bf(a0[4]+a1[4]+a2[4]+a3[4]) | ((uint)f2bf(a0[5]+a1[5]+a2[5]+a3[5]) << 16);
    o.w = (uint)f2bf(a0[6]+a1[6]+a2[6]+a3[6]) | ((uint)f2bf(a0[7]+a1[7]+a2[7]+a3[7]) << 16);
    *reinterpret_cast<uint4*>(&dst[(size_t)i * F + f8]) = o;
}

// ---------------- MFMA dense transform ----------------
// 512 threads = 8 waves, 2(M) x 4(N) grid over BM=64 rows; A-fragments in
// registers, per 16-col tile all KS B-loads issued as one independent batch.
// Fragment layouts (m89/m91-verified): A/B lane l -> row l&15, k=(l>>4)*8+e;
// C/D: col=lane&15, row=(lane>>4)*4+reg.

template <int K, int KPAD, int LDA, int F, int WA, int WB, int WC>
__global__ __launch_bounds__(512) void mfma_transform_k(
        const ushort* __restrict__ inA, const ushort* __restrict__ inB,
        const ushort* __restrict__ inC, const ushort* __restrict__ Wt,
        const float* __restrict__ bias, ushort* __restrict__ out, int N) {
    constexpr int KS = KPAD / 32;
    constexpr int FW = F / 4;
    constexpr int NT = FW / 16;
    __shared__ ushort At[64 * LDA];
    const int node0 = blockIdx.x * 64;
    const int tid = threadIdx.x;
    const int lane = tid & 63;
    const int wv = tid >> 6;
    const int wm = wv & 1;
    const int wn = wv >> 1;

    {
        constexpr int NV = WA / 8;
        for (int idx = tid; idx < 64 * NV; idx += 512) {
            int m = idx / NV, q = idx - m * NV;
            int i = node0 + m;
            uint4 v = make_uint4(0, 0, 0, 0);
            if (i < N) v = *reinterpret_cast<const uint4*>(&inA[(size_t)i * WA + q * 8]);
            *reinterpret_cast<uint4*>(&At[m * LDA + q * 8]) = v;
        }
    }
    if constexpr (WB > 0) {
        constexpr int NV = WB / 8;
        for (int idx = tid; idx < 64 * NV; idx += 512) {
            int m = idx / NV, q = idx - m * NV;
            int i = node0 + m;
            uint4 v = make_uint4(0, 0, 0, 0);
            if (i < N) v = *reinterpret_cast<const uint4*>(&inB[(size_t)i * WB + q * 8]);
            *reinterpret_cast<uint4*>(&At[m * LDA + WA + q * 8]) = v;
        }
    }
    if constexpr (WC > 0) {
        constexpr int NV = WC / 8;
        for (int idx = tid; idx < 64 * NV; idx += 512) {
            int m = idx / NV, q = idx - m * NV;
            int i = node0 + m;
            uint4 v = make_uint4(0, 0, 0, 0);
            if (i < N) v = *reinterpret_cast<const uint4*>(&inC[(size_t)i * WC + q * 8]);
            *reinterpret_cast<uint4*>(&At[m * LDA + WA + WB + q * 8]) = v;
        }
    }
    {
        constexpr int PAD = LDA - K;
        for (int idx = tid; idx < 64 * PAD; idx += 512) {
            int m = idx / PAD, k = K + (idx - m * PAD);
            At[m * LDA + k] = 0;
        }
    }
    __syncthreads();

    const int r15 = lane & 15, kg = lane >> 4;

    short8 a[2][KS];
    #pragma unroll
    for (int s = 0; s < 2; s++)
        #pragma unroll
        for (int kc = 0; kc < KS; kc++)
            a[s][kc] = *reinterpret_cast<const short8*>(
                &At[(wm * 32 + s * 16 + r15) * LDA + kg * 8 + kc * 32]);

    f32x4 acc[2][NT];
    #pragma unroll
    for (int s = 0; s < 2; s++)
        #pragma unroll
        for (int nt = 0; nt < NT; nt++) acc[s][nt] = (f32x4){0.f, 0.f, 0.f, 0.f};

    const ushort* wbase = &Wt[(size_t)(wn * FW + r15) * KPAD + kg * 8];
    #pragma unroll
    for (int nt = 0; nt < NT; nt++) {
        short8 b[KS];
        #pragma unroll
        for (int kc = 0; kc < KS; kc++)
            b[kc] = *reinterpret_cast<const short8*>(
                wbase + (size_t)nt * 16 * KPAD + kc * 32);
        #pragma unroll
        for (int kc = 0; kc < KS; kc++) {
            acc[0][nt] = __builtin_amdgcn_mfma_f32_16x16x32_bf16(a[0][kc], b[kc], acc[0][nt], 0, 0, 0);
            acc[1][nt] = __builtin_amdgcn_mfma_f32_16x16x32_bf16(a[1][kc], b[kc], acc[1][nt], 0, 0, 0);
        }
    }

    #pragma unroll
    for (int s = 0; s < 2; s++)
        #pragma unroll
        for (int nt = 0; nt < NT; nt++) {
            int colg = wn * FW + nt * 16 + r15;
            float bv = bias[colg];
            #pragma unroll
            for (int reg = 0; reg < 4; reg++) {
                int row = node0 + wm * 32 + s * 16 + kg * 4 + reg;
                if (row < N) {
                    float v = fmaxf(acc[s][nt][reg] + bv, 0.f);
                    out[(size_t)row * F + colg] = f2bf(v);
                }
            }
        }
}

// ---------------- pool: pooled[g][c] = max over rows of graph g ----------------

#define PSPLIT 8
__global__ __launch_bounds__(256) void pool_k(const ushort* __restrict__ h3,
                                              const int* __restrict__ gstart,
                                              float* __restrict__ pooled) {
    int g = blockIdx.x, sp = blockIdx.y, c = threadIdx.x;
    int i0 = gstart[g], i1 = gstart[g + 1];
    int len = i1 - i0;
    int per = (len + PSPLIT - 1) / PSPLIT;
    int s = i0 + sp * per;
    int e = min(s + per, i1);
    if (s >= e) return;
    float m0 = 0.f, m1 = 0.f, m2 = 0.f, m3 = 0.f;
    int i = s;
    for (; i + 3 < e; i += 4) {
        m0 = fmaxf(m0, __uint_as_float((uint)h3[(size_t)i * 256 + c] << 16));
        m1 = fmaxf(m1, __uint_as_float((uint)h3[(size_t)(i + 1) * 256 + c] << 16));
        m2 = fmaxf(m2, __uint_as_float((uint)h3[(size_t)(i + 2) * 256 + c] << 16));
        m3 = fmaxf(m3, __uint_as_float((uint)h3[(size_t)(i + 3) * 256 + c] << 16));
    }
    for (; i < e; i++)
        m0 = fmaxf(m0, __uint_as_float((uint)h3[(size_t)i * 256 + c] << 16));
    float mm = fmaxf(fmaxf(m0, m1), fmaxf(m2, m3));
    atomicMax(reinterpret_cast<int*>(&pooled[g * 256 + c]), __float_as_int(mm));
}

// ---------------- head: logits -> log_softmax, softmax ----------------

__global__ __launch_bounds__(320) void head_k(const float* __restrict__ pooled,
                                              const float* __restrict__ Wl,
                                              const float* __restrict__ bl,
                                              float* __restrict__ out) {
    __shared__ float lg[GG][10];
    __shared__ float lse[GG];
    int t = threadIdx.x;
    int g = t / 10, c = t % 10;
    float acc = bl[c];
    for (int k = 0; k < 256; k++) acc = fmaf(pooled[g * 256 + k], Wl[k * 10 + c], acc);
    lg[g][c] = acc;
    __syncthreads();
    if (c == 0) {
        float mx = -1e30f;
        for (int j = 0; j < 10; j++) mx = fmaxf(mx, lg[g][j]);
        float s = 0.f;
        for (int j = 0; j < 10; j++) s += expf(lg[g][j] - mx);
        lse[g] = mx + logf(s);
    }
    __syncthreads();
    float o = acc - lse[g];
    out[g * 10 + c] = o;             // log_softmax
    out[320 + g * 10 + c] = expf(o); // softmax(log_softmax(x)) == exp(log_softmax(x))
}

// ---------------- launch ----------------

extern "C" void kernel_launch(void* const* d_in, const int* in_sizes, int n_in,
                              void* d_out, int out_size, void* d_ws, size_t ws_size,
                              hipStream_t stream) {
    const int N = NN, E = EE;
    const float* nrm = (const float*)d_in[0];
    const float* pos = (const float*)d_in[1];
    const float* x   = (const float*)d_in[2];
    const int* ei    = (const int*)d_in[3];
    const int* batch = (const int*)d_in[4];
    const float* W1 = (const float*)d_in[5];
    const float* b1 = (const float*)d_in[6];
    const float* W2 = (const float*)d_in[7];
    const float* b2 = (const float*)d_in[8];
    const float* W3 = (const float*)d_in[9];
    const float* b3 = (const float*)d_in[10];
    const float* Wl = (const float*)d_in[11];
    const float* bl = (const float*)d_in[12];

    const int* esrc = ei;
    const int* edst = ei + E;

    char* w = (char*)d_ws;
    auto carve = [&](size_t bytes) {
        void* p = (void*)w;
        w += (bytes + 255) & ~(size_t)255;
        return p;
    };
    int* hist     = (int*)carve((size_t)MH * 4);
    int* ofs      = (int*)carve((size_t)MH * 4);
    int* bsum     = (int*)carve((size_t)NB2 * 4);
    uint* packed  = (uint*)carve((size_t)E * 4);
    int* rowptr   = (int*)carve((size_t)(N + 1) * 4);
    ushort* col   = (ushort*)carve((size_t)E * 2);
    int* gstart   = (int*)carve((size_t)(GG + 1) * 4);
    ushort* inpb  = (ushort*)carve((size_t)N * 8 * 2);
    ushort* agg1  = (ushort*)carve((size_t)N * 8 * 2);
    ushort* h1    = (ushort*)carve((size_t)N * 64 * 2);
    ushort* aggh1 = (ushort*)carve((size_t)N * 64 * 2);
    ushort* h2    = (ushort*)carve((size_t)N * 128 * 2);
    ushort* aggh2 = (ushort*)carve((size_t)N * 128 * 2);
    ushort* h3    = (ushort*)carve((size_t)N * 256 * 2);
    ushort* Wt1   = (ushort*)carve((size_t)64 * 32 * 2);
    ushort* Wt2   = (ushort*)carve((size_t)128 * 96 * 2);
    ushort* Wt3   = (ushort*)carve((size_t)256 * 224 * 2);
    float* pooled = (float*)carve((size_t)GG * 256 * 4);

    hipMemsetAsync(pooled, 0, (size_t)GG * 256 * 4, stream);

    // CSR build: LDS bucket sort
    bhist_k<<<NBLK1, 256, 0, stream>>>(edst, hist);
    scan1_k<<<NB2, SCB, 0, stream>>>(hist, bsum, MH);
    scan2g_k<<<1, 64, 0, stream>>>(bsum, NB2);
    scan3g_k<<<NB2, SCB, 0, stream>>>(hist, bsum, ofs, MH);
    bsort1_k<<<NBLK1, 256, 0, stream>>>(esrc, edst, ofs, packed);
    bsort2_k<<<NBUK, 256, 0, stream>>>(packed, ofs, col, rowptr);

    // setup
    prep_k<<<(N + 255) / 256, 256, 0, stream>>>(nrm, pos, x, batch, inpb, gstart, N);
    {
        const int TOT = 64 * 32 + 128 * 96 + 256 * 224;
        wtp_all_k<<<(TOT + 255) / 256, 256, 0, stream>>>(W1, Wt1, W2, Wt2, W3, Wt3);
    }

    // layer 1
    aggb_k<8><<<(N + 255) / 256, 256, 0, stream>>>(rowptr, col, inpb, agg1, N);
    mfma_transform_k<8, 32, 40, 64, 8, 0, 0><<<(N + 63) / 64, 512, 0, stream>>>(
        agg1, nullptr, nullptr, Wt1, b1, h1, N);

    // layer 2
    aggb_k<64><<<(N + 31) / 32, 256, 0, stream>>>(rowptr, col, h1, aggh1, N);
    mfma_transform_k<72, 96, 104, 128, 64, 8, 0><<<(N + 63) / 64, 512, 0, stream>>>(
        aggh1, agg1, nullptr, Wt2, b2, h2, N);

    // layer 3
    aggb_k<128><<<(N + 15) / 16, 256, 0, stream>>>(rowptr, col, h2, aggh2, N);
    mfma_transform_k<200, 224, 232, 256, 64, 8, 128><<<(N + 63) / 64, 512, 0, stream>>>(
        aggh1, agg1, aggh2, Wt3, b3, h3, N);

    // pool + head
    pool_k<<<dim3(GG, PSPLIT), 256, 0, stream>>>(h3, gstart, pooled);
    head_k<<<1, 320, 0, stream>>>(pooled, Wl, bl, (float*)d_out);
}

// Round 9
// 138.590 us; speedup vs baseline: 4.5674x; 1.3408x over previous
//
#include <hip/hip_runtime.h>
#include <hip/hip_bf16.h>

#define NN 50000
#define EE 800000
#define GG 32
#define SCB 512

// bucket sort geometry (bucket = 64 dst nodes = one layer-block)
#define BSH 6
#define NBUK 782                      // ceil(50000/64)
#define NBLK1 256                     // edge blocks in pass 1
#define EPB (EE / NBLK1)              // 3125 edges per block
#define MH (NBUK * NBLK1)             // 200192 counters
#define NB2 ((MH + SCB - 1) / SCB)    // 391 scan blocks
#define CAP2 2048                     // max edges per bucket (mean 1023)

#define B_PREP ((NN + 255) / 256)                 // 196
#define TOTW (64 * 32 + 128 * 96 + 256 * 224)     // 71680
#define B_WTP ((TOTW + 255) / 256)                // 280

using short8 = __attribute__((ext_vector_type(8))) short;
using f32x4  = __attribute__((ext_vector_type(4))) float;

__device__ __forceinline__ ushort f2bf(float f) {
    __hip_bfloat16 hb = __float2bfloat16(f);
    return *reinterpret_cast<ushort*>(&hb);
}

__device__ __forceinline__ void acc8(uint4 v, float* a) {
    a[0] += __uint_as_float(v.x << 16); a[1] += __uint_as_float(v.x & 0xffff0000u);
    a[2] += __uint_as_float(v.y << 16); a[3] += __uint_as_float(v.y & 0xffff0000u);
    a[4] += __uint_as_float(v.z << 16); a[5] += __uint_as_float(v.z & 0xffff0000u);
    a[6] += __uint_as_float(v.w << 16); a[7] += __uint_as_float(v.w & 0xffff0000u);
}

// Wt[n][k'] = W[k][n]; mode 1 = fold W3 rows 200:208 into 64:72;
// mode 2 = layer-2 K-permutation so A-layout is [agg1(8)|aggh1(64)].
__device__ __forceinline__ void wtp_one(const float* W, ushort* Wt, int K, int F,
                                        int KPAD, int mode, int idx) {
    int n = idx / KPAD, k = idx - n * KPAD;
    float v = 0.f;
    if (k < K) {
        int ko = k;
        if (mode == 2) ko = (k < 8) ? (k + 64) : (k - 8);
        v = W[(size_t)ko * F + n];
        if (mode == 1 && ko >= 64 && ko < 72) v += W[(size_t)(ko + 136) * F + n];
    }
    Wt[idx] = f2bf(v);
}

// ---------------- fused setup: bhist | inp-build | Wt build | pooled init ----------------

__global__ __launch_bounds__(256) void setup_k(
        const int* __restrict__ edst, int* __restrict__ hist,
        const float* __restrict__ nrm, const float* __restrict__ pos,
        const float* __restrict__ x, ushort* __restrict__ inpb,
        const float* __restrict__ W1, ushort* __restrict__ Wt1,
        const float* __restrict__ W2, ushort* __restrict__ Wt2,
        const float* __restrict__ W3, ushort* __restrict__ Wt3,
        float* __restrict__ pooled) {
    int blk = blockIdx.x, tid = threadIdx.x;
    if (blk < NBLK1) {                       // per-(bucket,block) histogram
        __shared__ uint cnt[NBUK];
        for (int i = tid; i < NBUK; i += 256) cnt[i] = 0;
        __syncthreads();
        int base = blk * EPB;
        for (int i = tid; i < EPB; i += 256)
            atomicAdd(&cnt[(uint)edst[base + i] >> BSH], 1u);
        __syncthreads();
        for (int b = tid; b < NBUK; b += 256)
            hist[(size_t)b * NBLK1 + blk] = (int)cnt[b];
    } else if (blk < NBLK1 + B_PREP) {       // inp concat -> bf16
        int i = (blk - NBLK1) * 256 + tid;
        if (i < NN) {
            float v[8];
            v[0] = nrm[i * 3]; v[1] = nrm[i * 3 + 1]; v[2] = nrm[i * 3 + 2];
            v[3] = pos[i * 3]; v[4] = pos[i * 3 + 1]; v[5] = pos[i * 3 + 2];
            v[6] = x[i * 2];   v[7] = x[i * 2 + 1];
            uint4 d;
            d.x = (uint)f2bf(v[0]) | ((uint)f2bf(v[1]) << 16);
            d.y = (uint)f2bf(v[2]) | ((uint)f2bf(v[3]) << 16);
            d.z = (uint)f2bf(v[4]) | ((uint)f2bf(v[5]) << 16);
            d.w = (uint)f2bf(v[6]) | ((uint)f2bf(v[7]) << 16);
            *reinterpret_cast<uint4*>(&inpb[(size_t)i * 8]) = d;
        }
    } else if (blk < NBLK1 + B_PREP + B_WTP) { // transposed bf16 weights
        int idx = (blk - NBLK1 - B_PREP) * 256 + tid;
        if (idx < 64 * 32) { wtp_one(W1, Wt1, 8, 64, 32, 0, idx); return; }
        idx -= 64 * 32;
        if (idx < 128 * 96) { wtp_one(W2, Wt2, 72, 128, 96, 2, idx); return; }
        idx -= 128 * 96;
        if (idx < 256 * 224) wtp_one(W3, Wt3, 200, 256, 224, 1, idx);
    } else {                                  // pooled = 0
        for (int q = tid; q < GG * 256; q += 256) pooled[q] = 0.f;
    }
}

// ---------------- generic 3-phase exclusive scan ----------------

__global__ __launch_bounds__(SCB) void scan1_k(const int* __restrict__ in,
                                               int* __restrict__ bsum, int M) {
    __shared__ int ws[SCB / 64];
    int tid = threadIdx.x, lane = tid & 63, w = tid >> 6;
    int i = blockIdx.x * SCB + tid;
    int s = (i < M) ? in[i] : 0;
    #pragma unroll
    for (int off = 32; off >= 1; off >>= 1) s += __shfl_down(s, off, 64);
    if (lane == 0) ws[w] = s;
    __syncthreads();
    if (tid == 0) {
        int t = 0;
        #pragma unroll
        for (int j = 0; j < SCB / 64; j++) t += ws[j];
        bsum[blockIdx.x] = t;
    }
}

__global__ __launch_bounds__(64) void scan2g_k(int* __restrict__ bsum, int nb) {
    int lane = threadIdx.x;
    int carry = 0;
    for (int base = 0; base < nb; base += 64) {
        int v = (base + lane < nb) ? bsum[base + lane] : 0;
        int s = v;
        #pragma unroll
        for (int off = 1; off < 64; off <<= 1) {
            int t = __shfl_up(s, off, 64);
            if (lane >= off) s += t;
        }
        if (base + lane < nb) bsum[base + lane] = carry + s - v;
        carry += __shfl(s, 63, 64);
    }
}

__global__ __launch_bounds__(SCB) void scan3g_k(const int* __restrict__ in,
                                                const int* __restrict__ bsum,
                                                int* __restrict__ out, int M) {
    __shared__ int ws[SCB / 64];
    int tid = threadIdx.x, lane = tid & 63, w = tid >> 6;
    int i = blockIdx.x * SCB + tid;
    int v = (i < M) ? in[i] : 0;
    int s = v;
    #pragma unroll
    for (int off = 1; off < 64; off <<= 1) {
        int t = __shfl_up(s, off, 64);
        if (lane >= off) s += t;
    }
    if (lane == 63) ws[w] = s;
    __syncthreads();
    if (w == 0 && lane < SCB / 64) {
        int t = ws[lane];
        #pragma unroll
        for (int off = 1; off < SCB / 64; off <<= 1) {
            int u = __shfl_up(t, off, 64);
            if (lane >= off) t += u;
        }
        ws[lane] = t;
    }
    __syncthreads();
    if (i < M) out[i] = (w ? ws[w - 1] : 0) + s - v + bsum[blockIdx.x];
}

// ---------------- bucket sort pass 1: LDS sort + coalesced packed writes ----------------

__global__ __launch_bounds__(256) void bsort1_k(const int* __restrict__ esrc,
                                                const int* __restrict__ edst,
                                                const int* __restrict__ ofs,
                                                uint* __restrict__ packed) {
    __shared__ uint cnt[1024];
    __shared__ uint lofs0[1024];
    __shared__ uint goff[NBUK];
    __shared__ uint stage[EPB];
    __shared__ uint wsum[4];
    int tid = threadIdx.x, blk = blockIdx.x;
    int lane = tid & 63, wv = tid >> 6;

    for (int i = tid; i < 1024; i += 256) cnt[i] = 0;
    __syncthreads();
    int base = blk * EPB;
    for (int i = tid; i < EPB; i += 256)
        atomicAdd(&cnt[(uint)edst[base + i] >> BSH], 1u);
    __syncthreads();

    uint c0 = cnt[tid * 4 + 0], c1 = cnt[tid * 4 + 1];
    uint c2 = cnt[tid * 4 + 2], c3 = cnt[tid * 4 + 3];
    uint ts = c0 + c1 + c2 + c3;
    uint sc = ts;
    #pragma unroll
    for (int off = 1; off < 64; off <<= 1) {
        uint t = __shfl_up(sc, off, 64);
        if (lane >= off) sc += t;
    }
    if (lane == 63) wsum[wv] = sc;
    __syncthreads();
    uint wbase = 0;
    for (int j = 0; j < wv; j++) wbase += wsum[j];
    uint run = wbase + sc - ts;
    lofs0[tid * 4 + 0] = run;
    lofs0[tid * 4 + 1] = run + c0;
    lofs0[tid * 4 + 2] = run + c0 + c1;
    lofs0[tid * 4 + 3] = run + c0 + c1 + c2;
    cnt[tid * 4 + 0] = run;
    cnt[tid * 4 + 1] = run + c0;
    cnt[tid * 4 + 2] = run + c0 + c1;
    cnt[tid * 4 + 3] = run + c0 + c1 + c2;
    for (int b = tid; b < NBUK; b += 256)
        goff[b] = (uint)ofs[(size_t)b * NBLK1 + blk];
    __syncthreads();

    for (int i = tid; i < EPB; i += 256) {
        int d = edst[base + i];
        uint b = (uint)d >> BSH;
        uint pos = atomicAdd(&cnt[b], 1u);
        stage[pos] = (b << 22) | ((uint)(d & 63) << 16) | (uint)esrc[base + i];
    }
    __syncthreads();

    for (int i = tid; i < EPB; i += 256) {
        uint p = stage[i];
        uint b = p >> 22;
        packed[goff[b] + ((uint)i - lofs0[b])] = p & 0x3FFFFFu;
    }
}

// ---------------- bucket sort pass 2: fine sort -> col + rowptr ----------------

__global__ __launch_bounds__(256) void bsort2_k(const uint* __restrict__ packed,
                                                const int* __restrict__ ofs,
                                                ushort* __restrict__ col,
                                                int* __restrict__ rowptr) {
    __shared__ uint buf[CAP2];
    __shared__ ushort srt[CAP2];
    __shared__ uint fcnt[64], fofs[64];
    int b = blockIdx.x, tid = threadIdx.x;
    uint g0 = (uint)ofs[(size_t)b * NBLK1];
    uint g1 = (b + 1 < NBUK) ? (uint)ofs[(size_t)(b + 1) * NBLK1] : (uint)EE;
    uint n = g1 - g0;
    if (tid < 64) fcnt[tid] = 0;
    __syncthreads();
    for (uint i = tid; i < n; i += 256) {
        uint p = packed[g0 + i];
        buf[i] = p;
        atomicAdd(&fcnt[(p >> 16) & 63], 1u);
    }
    __syncthreads();
    if (tid < 64) {
        uint v = fcnt[tid], s = v;
        #pragma unroll
        for (int off = 1; off < 64; off <<= 1) {
            uint t = __shfl_up(s, off, 64);
            if (tid >= off) s += t;
        }
        uint e0 = s - v;
        fofs[tid] = e0;
        int node = (b << BSH) + tid;
        if (node < NN) rowptr[node] = (int)(g0 + e0);
    }
    if (b == NBUK - 1 && tid == 0) rowptr[NN] = EE;
    __syncthreads();
    for (uint i = tid; i < n; i += 256) {
        uint p = buf[i];
        uint pos = atomicAdd(&fofs[(p >> 16) & 63], 1u);
        srt[pos] = (ushort)(p & 0xFFFFu);
    }
    __syncthreads();
    for (uint i = tid; i < n; i += 256) col[g0 + i] = srt[i];
}

// ---------------- fused layer: gather-aggregate + MFMA transform (+ pool) ----------------
// Block = 64 nodes (== one bucket; edge range contiguous), 512 threads = 8 waves.
// A-layout: [preA(WPA) | preB(WPB) | gathered(WG)] = K cols, zero-pad to KPAD.
// Phase A: TPN threads/node aggregate gsrc rows over the node's CSR edges into
// f32 registers, emit bf16 into LDS At (and optionally aggout global).
// Phase B: 2(M)x4(N) wave grid MFMA (m89/m91-verified fragment layouts:
// A/B lane l -> row l&15, k=(l>>4)*8+e; C/D col=lane&15, row=(lane>>4)*4+reg),
// B-loads batched KS-deep per 16-col tile (R6 lesson).
// POOL: h3 tile -> LDS (At reused, LDA>=256), segmented max over sorted batch,
// <=3 atomicMax per (thread,col) -- h3 never touches global memory.

template <int K, int KPAD, int LDA, int F, int WPA, int WPB, int WG, bool POOL>
__global__ __launch_bounds__(512) void layer_k(
        const ushort* __restrict__ preA, const ushort* __restrict__ preB,
        const ushort* __restrict__ gsrc,
        const int* __restrict__ rowptr, const ushort* __restrict__ col,
        const ushort* __restrict__ Wt, const float* __restrict__ bias,
        ushort* __restrict__ aggout, ushort* __restrict__ out,
        const int* __restrict__ batch, float* __restrict__ pooled, int N) {
    constexpr int WPRE = WPA + WPB;
    constexpr int NU4 = WG / 8;
    constexpr int TPN = (NU4 < 8) ? NU4 : 8;
    constexpr int U4PT = NU4 / TPN;
    constexpr int KS = KPAD / 32;
    constexpr int FW = F / 4;
    constexpr int NT = FW / 16;

    __shared__ ushort At[64 * LDA];
    __shared__ int batchv[64];

    const int node0 = blockIdx.x * 64;
    const int tid = threadIdx.x;
    const int lane = tid & 63;
    const int wv = tid >> 6;
    const int wm = wv & 1;
    const int wn = wv >> 1;

    // ---- phase A: gather-aggregate into At[., WPRE..WPRE+WG) ----
    {
        int m = tid / TPN;
        int j = tid - m * TPN;
        if (m < 64) {
            int i = node0 + m;
            float ga0[U4PT * 8], ga1[U4PT * 8];
            #pragma unroll
            for (int q = 0; q < U4PT * 8; q++) { ga0[q] = 0.f; ga1[q] = 0.f; }
            if (i < N) {
                int e0 = rowptr[i], e1 = rowptr[i + 1];
                int e = e0;
                for (; e + 1 < e1; e += 2) {
                    int s0 = col[e], s1 = col[e + 1];
                    #pragma unroll
                    for (int u = 0; u < U4PT; u++) {
                        uint4 v0 = *reinterpret_cast<const uint4*>(
                            &gsrc[(size_t)s0 * WG + (j * U4PT + u) * 8]);
                        uint4 v1 = *reinterpret_cast<const uint4*>(
                            &gsrc[(size_t)s1 * WG + (j * U4PT + u) * 8]);
                        acc8(v0, ga0 + u * 8);
                        acc8(v1, ga1 + u * 8);
                    }
                }
                if (e < e1) {
                    int s0 = col[e];
                    #pragma unroll
                    for (int u = 0; u < U4PT; u++) {
                        uint4 v0 = *reinterpret_cast<const uint4*>(
                            &gsrc[(size_t)s0 * WG + (j * U4PT + u) * 8]);
                        acc8(v0, ga0 + u * 8);
                    }
                }
            }
            #pragma unroll
            for (int u = 0; u < U4PT; u++) {
                uint4 o;
                o.x = (uint)f2bf(ga0[u*8+0] + ga1[u*8+0]) | ((uint)f2bf(ga0[u*8+1] + ga1[u*8+1]) << 16);
                o.y = (uint)f2bf(ga0[u*8+2] + ga1[u*8+2]) | ((uint)f2bf(ga0[u*8+3] + ga1[u*8+3]) << 16);
                o.z = (uint)f2bf(ga0[u*8+4] + ga1[u*8+4]) | ((uint)f2bf(ga0[u*8+5] + ga1[u*8+5]) << 16);
                o.w = (uint)f2bf(ga0[u*8+6] + ga1[u*8+6]) | ((uint)f2bf(ga0[u*8+7] + ga1[u*8+7]) << 16);
                *reinterpret_cast<uint4*>(&At[m * LDA + WPRE + (j * U4PT + u) * 8]) = o;
                if (aggout != nullptr && i < N)
                    *reinterpret_cast<uint4*>(&aggout[(size_t)i * WG + (j * U4PT + u) * 8]) = o;
            }
        }
        if constexpr (POOL) {
            if (tid < 64) batchv[tid] = (node0 + tid < N) ? batch[node0 + tid] : -1;
        }
    }

    // ---- pre-staged cols [0, WPRE) from global ----
    if constexpr (WPRE > 0) {
        constexpr int NP = WPRE / 8;
        for (int idx = tid; idx < 64 * NP; idx += 512) {
            int m = idx / NP, q = idx - m * NP;
            int i = node0 + m;
            uint4 v = make_uint4(0, 0, 0, 0);
            if (i < N) {
                int c = q * 8;
                if (c < WPA) v = *reinterpret_cast<const uint4*>(&preA[(size_t)i * WPA + c]);
                else v = *reinterpret_cast<const uint4*>(&preB[(size_t)i * WPB + (c - WPA)]);
            }
            *reinterpret_cast<uint4*>(&At[m * LDA + q * 8]) = v;
        }
    }
    // ---- zero pad [K, KPAD) ----
    {
        constexpr int PADU4 = (KPAD - K) / 8;
        for (int idx = tid; idx < 64 * PADU4; idx += 512) {
            int m = idx / PADU4, q = idx - m * PADU4;
            *reinterpret_cast<uint4*>(&At[m * LDA + K + q * 8]) = make_uint4(0, 0, 0, 0);
        }
    }
    __syncthreads();

    // ---- phase B: MFMA ----
    const int r15 = lane & 15, kg = lane >> 4;

    short8 a[2][KS];
    #pragma unroll
    for (int s = 0; s < 2; s++)
        #pragma unroll
        for (int kc = 0; kc < KS; kc++)
            a[s][kc] = *reinterpret_cast<const short8*>(
                &At[(wm * 32 + s * 16 + r15) * LDA + kg * 8 + kc * 32]);

    f32x4 acc[2][NT];
    #pragma unroll
    for (int s = 0; s < 2; s++)
        #pragma unroll
        for (int nt = 0; nt < NT; nt++) acc[s][nt] = (f32x4){0.f, 0.f, 0.f, 0.f};

    const ushort* wbase = &Wt[(size_t)(wn * FW + r15) * KPAD + kg * 8];
    #pragma unroll
    for (int nt = 0; nt < NT; nt++) {
        short8 b[KS];
        #pragma unroll
        for (int kc = 0; kc < KS; kc++)
            b[kc] = *reinterpret_cast<const short8*>(
                wbase + (size_t)nt * 16 * KPAD + kc * 32);
        #pragma unroll
        for (int kc = 0; kc < KS; kc++) {
            acc[0][nt] = __builtin_amdgcn_mfma_f32_16x16x32_bf16(a[0][kc], b[kc], acc[0][nt], 0, 0, 0);
            acc[1][nt] = __builtin_amdgcn_mfma_f32_16x16x32_bf16(a[1][kc], b[kc], acc[1][nt], 0, 0, 0);
        }
    }

    if constexpr (!POOL) {
        #pragma unroll
        for (int s = 0; s < 2; s++)
            #pragma unroll
            for (int nt = 0; nt < NT; nt++) {
                int colg = wn * FW + nt * 16 + r15;
                float bv = bias[colg];
                #pragma unroll
                for (int reg = 0; reg < 4; reg++) {
                    int row = node0 + wm * 32 + s * 16 + kg * 4 + reg;
                    if (row < N) {
                        float v = fmaxf(acc[s][nt][reg] + bv, 0.f);
                        out[(size_t)row * F + colg] = f2bf(v);
                    }
                }
            }
    } else {
        // h3 tile -> LDS (reuse At; LDA >= 256), then segmented max pool
        __syncthreads();
        ushort* H3 = At;
        #pragma unroll
        for (int s = 0; s < 2; s++)
            #pragma unroll
            for (int nt = 0; nt < NT; nt++) {
                int colg = wn * FW + nt * 16 + r15;
                float bv = bias[colg];
                #pragma unroll
                for (int reg = 0; reg < 4; reg++) {
                    int m = wm * 32 + s * 16 + kg * 4 + reg;
                    float v = fmaxf(acc[s][nt][reg] + bv, 0.f);
                    H3[m * 256 + colg] = f2bf(v);
                }
            }
        __syncthreads();
        int nvalid = min(64, N - node0);
        int c = tid & 255, half = tid >> 8;
        int m0 = half * 32;
        int m1 = min(m0 + 32, nvalid);
        int curg = -1;
        float cm = 0.f;
        for (int m = m0; m < m1; m++) {
            int g = batchv[m];
            if (g != curg) {
                if (curg >= 0)
                    atomicMax(reinterpret_cast<int*>(&pooled[curg * 256 + c]),
                              __float_as_int(cm));
                curg = g;
                cm = 0.f;
            }
            cm = fmaxf(cm, __uint_as_float((uint)H3[m * 256 + c] << 16));
        }
        if (curg >= 0)
            atomicMax(reinterpret_cast<int*>(&pooled[curg * 256 + c]),
                      __float_as_int(cm));
    }
}

// ---------------- head: logits -> log_softmax, softmax ----------------

__global__ __launch_bounds__(320) void head_k(const float* __restrict__ pooled,
                                              const float* __restrict__ Wl,
                                              const float* __restrict__ bl,
                                              float* __restrict__ out) {
    __shared__ float lg[GG][10];
    __shared__ float lse[GG];
    int t = threadIdx.x;
    int g = t / 10, c = t % 10;
    float acc = bl[c];
    for (int k = 0; k < 256; k++) acc = fmaf(pooled[g * 256 + k], Wl[k * 10 + c], acc);
    lg[g][c] = acc;
    __syncthreads();
    if (c == 0) {
        float mx = -1e30f;
        for (int j = 0; j < 10; j++) mx = fmaxf(mx, lg[g][j]);
        float s = 0.f;
        for (int j = 0; j < 10; j++) s += expf(lg[g][j] - mx);
        lse[g] = mx + logf(s);
    }
    __syncthreads();
    float o = acc - lse[g];
    out[g * 10 + c] = o;             // log_softmax
    out[320 + g * 10 + c] = expf(o); // softmax(log_softmax(x)) == exp(log_softmax(x))
}

// ---------------- launch ----------------

extern "C" void kernel_launch(void* const* d_in, const int* in_sizes, int n_in,
                              void* d_out, int out_size, void* d_ws, size_t ws_size,
                              hipStream_t stream) {
    const int N = NN, E = EE;
    const float* nrm = (const float*)d_in[0];
    const float* pos = (const float*)d_in[1];
    const float* x   = (const float*)d_in[2];
    const int* ei    = (const int*)d_in[3];
    const int* batch = (const int*)d_in[4];
    const float* W1 = (const float*)d_in[5];
    const float* b1 = (const float*)d_in[6];
    const float* W2 = (const float*)d_in[7];
    const float* b2 = (const float*)d_in[8];
    const float* W3 = (const float*)d_in[9];
    const float* b3 = (const float*)d_in[10];
    const float* Wl = (const float*)d_in[11];
    const float* bl = (const float*)d_in[12];

    const int* esrc = ei;
    const int* edst = ei + E;

    char* w = (char*)d_ws;
    auto carve = [&](size_t bytes) {
        void* p = (void*)w;
        w += (bytes + 255) & ~(size_t)255;
        return p;
    };
    int* hist     = (int*)carve((size_t)MH * 4);
    int* ofs      = (int*)carve((size_t)MH * 4);
    int* bsum     = (int*)carve((size_t)NB2 * 4);
    uint* packed  = (uint*)carve((size_t)E * 4);
    int* rowptr   = (int*)carve((size_t)(N + 1) * 4);
    ushort* col   = (ushort*)carve((size_t)E * 2);
    ushort* inpb  = (ushort*)carve((size_t)N * 8 * 2);
    ushort* agg1  = (ushort*)carve((size_t)N * 8 * 2);
    ushort* h1    = (ushort*)carve((size_t)N * 64 * 2);
    ushort* aggh1 = (ushort*)carve((size_t)N * 64 * 2);
    ushort* h2    = (ushort*)carve((size_t)N * 128 * 2);
    ushort* Wt1   = (ushort*)carve((size_t)64 * 32 * 2);
    ushort* Wt2   = (ushort*)carve((size_t)128 * 96 * 2);
    ushort* Wt3   = (ushort*)carve((size_t)256 * 224 * 2);
    float* pooled = (float*)carve((size_t)GG * 256 * 4);

    // setup: bhist | inp | Wt | pooled-init (independent, one dispatch)
    setup_k<<<NBLK1 + B_PREP + B_WTP + 1, 256, 0, stream>>>(
        edst, hist, nrm, pos, x, inpb, W1, Wt1, W2, Wt2, W3, Wt3, pooled);

    // CSR via two-level bucket sort
    scan1_k<<<NB2, SCB, 0, stream>>>(hist, bsum, MH);
    scan2g_k<<<1, 64, 0, stream>>>(bsum, NB2);
    scan3g_k<<<NB2, SCB, 0, stream>>>(hist, bsum, ofs, MH);
    bsort1_k<<<NBLK1, 256, 0, stream>>>(esrc, edst, ofs, packed);
    bsort2_k<<<NBUK, 256, 0, stream>>>(packed, ofs, col, rowptr);

    // layer 1: A = [agg(inp)(8)]            -> h1, agg1
    layer_k<8, 32, 40, 64, 0, 0, 8, false><<<NBUK, 512, 0, stream>>>(
        nullptr, nullptr, inpb, rowptr, col, Wt1, b1, agg1, h1, nullptr, nullptr, N);

    // layer 2: A = [agg1(8) | agg(h1)(64)]  -> h2, aggh1   (Wt2 K-permuted)
    layer_k<72, 96, 104, 128, 8, 0, 64, false><<<NBUK, 512, 0, stream>>>(
        agg1, nullptr, h1, rowptr, col, Wt2, b2, aggh1, h2, nullptr, nullptr, N);

    // layer 3: A = [aggh1(64) | agg1(8) | agg(h2)(128)] -> pooled (fused max pool)
    layer_k<200, 224, 264, 256, 64, 8, 128, true><<<NBUK, 512, 0, stream>>>(
        aggh1, agg1, h2, rowptr, col, Wt3, b3, nullptr, nullptr, batch, pooled, N);

    head_k<<<1, 320, 0, stream>>>(pooled, Wl, bl, (float*)d_out);
}